// Round 1
// baseline (1571.762 us; speedup 1.0000x reference)
//
#include <hip/hip_runtime.h>
#include <cfloat>

#define HEADS 4
#define HIDC 128
#define HC 512
#define NEG 0.2f

// ---------------- fp32 tiled GEMM: C[M,N] = A[M,K] @ B[K,N] (+ bias) ----------------
#define BM 128
#define BN 128
#define BK 8
#define TM 8
#define TN 8

__global__ __launch_bounds__(256) void sgemm_kernel(
    const float* __restrict__ A, const float* __restrict__ B,
    float* __restrict__ C, const float* __restrict__ bias,
    int M, int N, int K)
{
    __shared__ float As[BK][BM];
    __shared__ float Bs[BK][BN];
    const int tid = threadIdx.x;
    const int tx = tid & 15;        // 16 cols of threads
    const int ty = tid >> 4;        // 16 rows of threads
    const int arow = tid >> 1;      // 0..127
    const int acol = (tid & 1) * 4; // 0 or 4
    const int brow = tid >> 5;      // 0..7
    const int bcol = (tid & 31) * 4;
    const int gArow = blockIdx.y * BM + arow;
    const int gBcol = blockIdx.x * BN + bcol;

    float acc[TM][TN];
#pragma unroll
    for (int i = 0; i < TM; i++)
#pragma unroll
        for (int j = 0; j < TN; j++) acc[i][j] = 0.f;

    const float* Ap = A + (size_t)gArow * K;
    for (int k0 = 0; k0 < K; k0 += BK) {
        float4 av = make_float4(0.f, 0.f, 0.f, 0.f);
        if (gArow < M) av = *(const float4*)(Ap + k0 + acol);
        As[acol + 0][arow] = av.x;
        As[acol + 1][arow] = av.y;
        As[acol + 2][arow] = av.z;
        As[acol + 3][arow] = av.w;
        float4 bv = *(const float4*)(B + (size_t)(k0 + brow) * N + gBcol);
        *(float4*)&Bs[brow][bcol] = bv;
        __syncthreads();
#pragma unroll
        for (int k = 0; k < BK; k++) {
            float af[TM], bf[TN];
            *(float4*)&af[0] = *(const float4*)&As[k][ty * TM];
            *(float4*)&af[4] = *(const float4*)&As[k][ty * TM + 4];
            *(float4*)&bf[0] = *(const float4*)&Bs[k][tx * TN];
            *(float4*)&bf[4] = *(const float4*)&Bs[k][tx * TN + 4];
#pragma unroll
            for (int i = 0; i < TM; i++)
#pragma unroll
                for (int j = 0; j < TN; j++)
                    acc[i][j] += af[i] * bf[j];
        }
        __syncthreads();
    }

    const int ccol = blockIdx.x * BN + tx * TN;
    float bb[TN];
#pragma unroll
    for (int j = 0; j < TN; j++) bb[j] = bias ? bias[ccol + j] : 0.f;
#pragma unroll
    for (int i = 0; i < TM; i++) {
        int grow = blockIdx.y * BM + ty * TM + i;
        if (grow < M) {
            float4 v0 = make_float4(acc[i][0] + bb[0], acc[i][1] + bb[1],
                                    acc[i][2] + bb[2], acc[i][3] + bb[3]);
            float4 v1 = make_float4(acc[i][4] + bb[4], acc[i][5] + bb[5],
                                    acc[i][6] + bb[6], acc[i][7] + bb[7]);
            *(float4*)(C + (size_t)grow * N + ccol) = v0;
            *(float4*)(C + (size_t)grow * N + ccol + 4) = v1;
        }
    }
}

// ---------------- CSR build (by dst), self-loops handled virtually ----------------
__global__ void count_kernel(const int* __restrict__ dst, int* __restrict__ deg, int E)
{
    int e = blockIdx.x * blockDim.x + threadIdx.x;
    if (e < E) atomicAdd(&deg[dst[e]], 1);
}

__global__ __launch_bounds__(256) void scan_kernel(
    const int* __restrict__ deg, int* __restrict__ rowptr, int* __restrict__ cursor, int Nn)
{
    __shared__ int sums[256];
    const int tid = threadIdx.x;
    const int chunk = (Nn + 255) >> 8;
    const int lo = tid * chunk;
    const int hi = min(lo + chunk, Nn);
    int s = 0;
    for (int i = lo; i < hi; ++i) s += deg[i];
    sums[tid] = s;
    __syncthreads();
    for (int off = 1; off < 256; off <<= 1) {
        int v = (tid >= off) ? sums[tid - off] : 0;
        __syncthreads();
        sums[tid] += v;
        __syncthreads();
    }
    int base = (tid == 0) ? 0 : sums[tid - 1];
    for (int i = lo; i < hi; ++i) {
        rowptr[i] = base;
        cursor[i] = base;
        base += deg[i];
    }
    if (tid == 255) rowptr[Nn] = sums[255];
}

__global__ void fill_kernel(const int* __restrict__ src, const int* __restrict__ dst,
                            int* __restrict__ cursor, int* __restrict__ eidx, int E)
{
    int e = blockIdx.x * blockDim.x + threadIdx.x;
    if (e < E) {
        int d = dst[e];
        int pos = atomicAdd(&cursor[d], 1);
        eidx[pos] = src[e];
    }
}

// ---------------- per-node attention logit coefficients ----------------
// a_src[n,h] = sum_c h[n,h,c]*att_src[h,c] ; likewise a_dst. one wave per (node,head)
__global__ __launch_bounds__(256) void att_kernel(
    const float* __restrict__ h, const float* __restrict__ atts, const float* __restrict__ attd,
    float* __restrict__ a_src, float* __restrict__ a_dst)
{
    const int node = blockIdx.x;
    const int wv = threadIdx.x >> 6;   // head
    const int lane = threadIdx.x & 63;
    const int off = wv * HIDC + 2 * lane;
    float2 hv = *(const float2*)(h + (size_t)node * HC + off);
    float2 sv = *(const float2*)(atts + off);
    float2 dv = *(const float2*)(attd + off);
    float ps = hv.x * sv.x + hv.y * sv.y;
    float pd = hv.x * dv.x + hv.y * dv.y;
#pragma unroll
    for (int o = 32; o >= 1; o >>= 1) {
        ps += __shfl_xor(ps, o);
        pd += __shfl_xor(pd, o);
    }
    if (lane == 0) {
        a_src[node * 4 + wv] = ps;
        a_dst[node * 4 + wv] = pd;
    }
}

// ---------------- gather + segment softmax + aggregate + bias + relu ----------------
// one block per node; wave w handles head w (128 channels, 2 per lane)
__global__ __launch_bounds__(256) void gather_kernel(
    const float* __restrict__ h, const float* __restrict__ a_src, const float* __restrict__ a_dst,
    const int* __restrict__ rowptr, const int* __restrict__ eidx,
    const float* __restrict__ bias, float* __restrict__ out)
{
    const int node = blockIdx.x;
    const int tid = threadIdx.x;
    const int wv = tid >> 6;
    const int lane = tid & 63;
    __shared__ float m_s[HEADS], is_s[HEADS];
    const int beg = rowptr[node];
    const int deg = rowptr[node + 1] - beg;   // real in-edges; +1 virtual self loop
    const float4 ad4 = *(const float4*)(a_dst + (size_t)node * 4);

    if (wv == 0) {
        float mx0 = -1e30f, mx1 = -1e30f, mx2 = -1e30f, mx3 = -1e30f;
        for (int e = lane; e <= deg; e += 64) {
            int s = (e == deg) ? node : eidx[beg + e];
            float4 as4 = *(const float4*)(a_src + (size_t)s * 4);
            float l0 = as4.x + ad4.x; l0 = l0 > 0.f ? l0 : NEG * l0;
            float l1 = as4.y + ad4.y; l1 = l1 > 0.f ? l1 : NEG * l1;
            float l2 = as4.z + ad4.z; l2 = l2 > 0.f ? l2 : NEG * l2;
            float l3 = as4.w + ad4.w; l3 = l3 > 0.f ? l3 : NEG * l3;
            mx0 = fmaxf(mx0, l0); mx1 = fmaxf(mx1, l1);
            mx2 = fmaxf(mx2, l2); mx3 = fmaxf(mx3, l3);
        }
#pragma unroll
        for (int o = 32; o >= 1; o >>= 1) {
            mx0 = fmaxf(mx0, __shfl_xor(mx0, o));
            mx1 = fmaxf(mx1, __shfl_xor(mx1, o));
            mx2 = fmaxf(mx2, __shfl_xor(mx2, o));
            mx3 = fmaxf(mx3, __shfl_xor(mx3, o));
        }
        float s0 = 0.f, s1 = 0.f, s2 = 0.f, s3 = 0.f;
        for (int e = lane; e <= deg; e += 64) {
            int s = (e == deg) ? node : eidx[beg + e];
            float4 as4 = *(const float4*)(a_src + (size_t)s * 4);
            float l0 = as4.x + ad4.x; l0 = l0 > 0.f ? l0 : NEG * l0;
            float l1 = as4.y + ad4.y; l1 = l1 > 0.f ? l1 : NEG * l1;
            float l2 = as4.z + ad4.z; l2 = l2 > 0.f ? l2 : NEG * l2;
            float l3 = as4.w + ad4.w; l3 = l3 > 0.f ? l3 : NEG * l3;
            s0 += __expf(l0 - mx0); s1 += __expf(l1 - mx1);
            s2 += __expf(l2 - mx2); s3 += __expf(l3 - mx3);
        }
#pragma unroll
        for (int o = 32; o >= 1; o >>= 1) {
            s0 += __shfl_xor(s0, o); s1 += __shfl_xor(s1, o);
            s2 += __shfl_xor(s2, o); s3 += __shfl_xor(s3, o);
        }
        if (lane == 0) {
            m_s[0] = mx0; m_s[1] = mx1; m_s[2] = mx2; m_s[3] = mx3;
            is_s[0] = 1.f / s0; is_s[1] = 1.f / s1; is_s[2] = 1.f / s2; is_s[3] = 1.f / s3;
        }
    }
    __syncthreads();

    const float m = m_s[wv];
    const float is = is_s[wv];
    const float ad = (wv == 0) ? ad4.x : (wv == 1) ? ad4.y : (wv == 2) ? ad4.z : ad4.w;
    const int coff = wv * HIDC + 2 * lane;
    float2 acc = make_float2(0.f, 0.f);
    for (int e = 0; e <= deg; ++e) {
        int s = (e == deg) ? node : eidx[beg + e];
        float l = a_src[(size_t)s * 4 + wv] + ad;
        l = l > 0.f ? l : NEG * l;
        float w = __expf(l - m) * is;
        float2 hv = *(const float2*)(h + (size_t)s * HC + coff);
        acc.x += w * hv.x;
        acc.y += w * hv.y;
    }
    float2 bv = *(const float2*)(bias + coff);
    float o0 = acc.x + bv.x; o0 = o0 > 0.f ? o0 : 0.f;
    float o1 = acc.y + bv.y; o1 = o1 > 0.f ? o1 : 0.f;
    *(float2*)(out + (size_t)node * HC + coff) = make_float2(o0, o1);
}

extern "C" void kernel_launch(void* const* d_in, const int* in_sizes, int n_in,
                              void* d_out, int out_size, void* d_ws, size_t ws_size,
                              hipStream_t stream)
{
    const float* x   = (const float*)d_in[0];
    const int*   ei  = (const int*)d_in[1];
    const float* W1  = (const float*)d_in[2];
    const float* a1s = (const float*)d_in[3];
    const float* a1d = (const float*)d_in[4];
    const float* b1  = (const float*)d_in[5];
    const float* W2  = (const float*)d_in[6];
    const float* a2s = (const float*)d_in[7];
    const float* a2d = (const float*)d_in[8];
    const float* b2  = (const float*)d_in[9];
    const float* Wfc = (const float*)d_in[10];
    const float* bfc = (const float*)d_in[11];
    float* out = (float*)d_out;

    const int Nn  = in_sizes[0] / 384;   // 50000
    const int E   = in_sizes[1] / 2;     // 500000
    const int IN  = 384;
    const int OUT = in_sizes[11];        // 384

    // workspace layout
    float* bufA  = (float*)d_ws;                       // [Nn, HC]
    float* bufB  = bufA + (size_t)Nn * HC;             // [Nn, HC]
    float* a_src = bufB + (size_t)Nn * HC;             // [Nn, 4]
    float* a_dst = a_src + (size_t)Nn * 4;             // [Nn, 4]
    int* deg    = (int*)(a_dst + (size_t)Nn * 4);      // [Nn]
    int* rowptr = deg + Nn;                            // [Nn+1]
    int* cursor = rowptr + Nn + 1;                     // [Nn]
    int* eidx   = cursor + Nn;                         // [E]

    const int* e_src = ei;
    const int* e_dst = ei + E;

    // CSR build (edge structure is an input; rebuild every call)
    hipMemsetAsync(deg, 0, Nn * sizeof(int), stream);
    const int eb = (E + 255) / 256;
    count_kernel<<<eb, 256, 0, stream>>>(e_dst, deg, E);
    scan_kernel<<<1, 256, 0, stream>>>(deg, rowptr, cursor, Nn);
    fill_kernel<<<eb, 256, 0, stream>>>(e_src, e_dst, cursor, eidx, E);

    const dim3 g1(HC / BN, (Nn + BM - 1) / BM);

    // layer 1
    sgemm_kernel<<<g1, 256, 0, stream>>>(x, W1, bufA, nullptr, Nn, HC, IN);
    att_kernel<<<Nn, 256, 0, stream>>>(bufA, a1s, a1d, a_src, a_dst);
    gather_kernel<<<Nn, 256, 0, stream>>>(bufA, a_src, a_dst, rowptr, eidx, b1, bufB);

    // layer 2
    sgemm_kernel<<<g1, 256, 0, stream>>>(bufB, W2, bufA, nullptr, Nn, HC, HC);
    att_kernel<<<Nn, 256, 0, stream>>>(bufA, a2s, a2d, a_src, a_dst);
    gather_kernel<<<Nn, 256, 0, stream>>>(bufA, a_src, a_dst, rowptr, eidx, b2, bufB);

    // final FC
    const dim3 g3(OUT / BN, (Nn + BM - 1) / BM);
    sgemm_kernel<<<g3, 256, 0, stream>>>(bufB, Wfc, out, bfc, Nn, OUT, HC);
}

// Round 2
// 966.859 us; speedup vs baseline: 1.6256x; 1.6256x over previous
//
#include <hip/hip_runtime.h>
#include <cfloat>
#include <cstdint>

#define HEADS 4
#define HIDC 128
#define HC 512
#define NEG 0.2f

typedef _Float16 half8 __attribute__((ext_vector_type(8)));
typedef float floatx4 __attribute__((ext_vector_type(4)));

// ---------------- f16 MFMA GEMM: C[M,N] = A[Mp,K](f16) @ Bt[N,K]^T(f16) (+bias) ----
// 128x128 tile, BK=32, 4 waves in 2x2, each wave 64x64 via 4x4 mfma_f32_16x16x32_f16.
// Staging via global_load_lds width=16 (lane-ordered contiguous LDS layout).
__global__ __launch_bounds__(256) void mfma_gemm(
    const _Float16* __restrict__ A,   // [Mp][K] row-major, Mp multiple of 128
    const _Float16* __restrict__ Bt,  // [N][K] row-major (i.e. B transposed)
    float* __restrict__ C,            // [M][N]
    const float* __restrict__ bias,   // [N] or null
    int M, int N, int K)
{
    __shared__ __align__(16) _Float16 As[128 * 32];
    __shared__ __align__(16) _Float16 Bs[128 * 32];

    const int tid = threadIdx.x;
    const int w = tid >> 6;
    const int lane = tid & 63;
    const int wr = (w >> 1) * 64;     // wave row offset in tile
    const int wc = (w & 1) * 64;      // wave col offset in tile

    const int rowBase = blockIdx.y * 128;
    const int colBase = blockIdx.x * 128;

    // staging: wave w, iter t covers 16 rows of the 128x32 tile.
    // lane -> (row = lane>>2 within group, 8-half chunk = lane&3); 16B per lane.
    const int sRow0 = (w * 2 + 0) * 16 + (lane >> 2);
    const int sRow1 = (w * 2 + 1) * 16 + (lane >> 2);
    const int sCol = (lane & 3) * 8;

    const _Float16* gA0 = A + (size_t)(rowBase + sRow0) * K + sCol;
    const _Float16* gA1 = A + (size_t)(rowBase + sRow1) * K + sCol;
    const _Float16* gB0 = Bt + (size_t)(colBase + sRow0) * K + sCol;
    const _Float16* gB1 = Bt + (size_t)(colBase + sRow1) * K + sCol;

    _Float16* lA0 = &As[(w * 2 + 0) * 512];   // 16 rows * 32 halves
    _Float16* lA1 = &As[(w * 2 + 1) * 512];
    _Float16* lB0 = &Bs[(w * 2 + 0) * 512];
    _Float16* lB1 = &Bs[(w * 2 + 1) * 512];

    floatx4 acc[4][4];
#pragma unroll
    for (int i = 0; i < 4; i++)
#pragma unroll
        for (int j = 0; j < 4; j++) acc[i][j] = {0.f, 0.f, 0.f, 0.f};

    const int q = lane >> 4;          // quad
    const int l16 = lane & 15;

    for (int k0 = 0; k0 < K; k0 += 32) {
        __builtin_amdgcn_global_load_lds(
            (const __attribute__((address_space(1))) unsigned int*)(gA0 + k0),
            (__attribute__((address_space(3))) unsigned int*)lA0, 16, 0, 0);
        __builtin_amdgcn_global_load_lds(
            (const __attribute__((address_space(1))) unsigned int*)(gA1 + k0),
            (__attribute__((address_space(3))) unsigned int*)lA1, 16, 0, 0);
        __builtin_amdgcn_global_load_lds(
            (const __attribute__((address_space(1))) unsigned int*)(gB0 + k0),
            (__attribute__((address_space(3))) unsigned int*)lB0, 16, 0, 0);
        __builtin_amdgcn_global_load_lds(
            (const __attribute__((address_space(1))) unsigned int*)(gB1 + k0),
            (__attribute__((address_space(3))) unsigned int*)lB1, 16, 0, 0);
        __syncthreads();

        half8 af[4], bf[4];
#pragma unroll
        for (int i = 0; i < 4; i++)
            af[i] = *(const half8*)&As[(wr + i * 16 + l16) * 32 + q * 8];
#pragma unroll
        for (int j = 0; j < 4; j++)
            bf[j] = *(const half8*)&Bs[(wc + j * 16 + l16) * 32 + q * 8];
#pragma unroll
        for (int i = 0; i < 4; i++)
#pragma unroll
            for (int j = 0; j < 4; j++)
                acc[i][j] = __builtin_amdgcn_mfma_f32_16x16x32_f16(af[i], bf[j], acc[i][j], 0, 0, 0);
        __syncthreads();
    }

    // epilogue: C/D layout col=lane&15, row=quad*4+reg
#pragma unroll
    for (int i = 0; i < 4; i++) {
#pragma unroll
        for (int j = 0; j < 4; j++) {
            const int col = colBase + wc + j * 16 + l16;
            const float bb = bias ? bias[col] : 0.f;
#pragma unroll
            for (int r = 0; r < 4; r++) {
                const int row = rowBase + wr + i * 16 + q * 4 + r;
                if (row < M) C[(size_t)row * N + col] = acc[i][j][r] + bb;
            }
        }
    }
}

// ---------------- dtype conversion ----------------
__global__ void convert_x_kernel(const float* __restrict__ x, _Float16* __restrict__ o, size_t nquads)
{
    size_t i = (size_t)blockIdx.x * blockDim.x + threadIdx.x;
    if (i < nquads) {
        float4 v = *(const float4*)(x + i * 4);
        _Float16* p = o + i * 4;
        p[0] = (_Float16)v.x; p[1] = (_Float16)v.y;
        p[2] = (_Float16)v.z; p[3] = (_Float16)v.w;
    }
}

// W[k][n] (fp32) -> Wt[n][k] (f16)
__global__ void convert_wT_kernel(const float* __restrict__ W, _Float16* __restrict__ Wt, int K, int N)
{
    int k = blockIdx.x * 64 + (threadIdx.x & 63);
    int n = blockIdx.y * 4 + (threadIdx.x >> 6);
    if (k < K && n < N) Wt[(size_t)n * K + k] = (_Float16)W[(size_t)k * N + n];
}

// ---------------- CSR build (by dst) ----------------
__global__ void count_kernel(const int* __restrict__ dst, int* __restrict__ deg, int E)
{
    int e = blockIdx.x * blockDim.x + threadIdx.x;
    if (e < E) atomicAdd(&deg[dst[e]], 1);
}

__global__ __launch_bounds__(256) void scan_kernel(
    const int* __restrict__ deg, int* __restrict__ rowptr, int* __restrict__ cursor, int Nn)
{
    __shared__ int sums[256];
    const int tid = threadIdx.x;
    const int chunk = (Nn + 255) >> 8;
    const int lo = tid * chunk;
    const int hi = min(lo + chunk, Nn);
    int s = 0;
    for (int i = lo; i < hi; ++i) s += deg[i];
    sums[tid] = s;
    __syncthreads();
    for (int off = 1; off < 256; off <<= 1) {
        int v = (tid >= off) ? sums[tid - off] : 0;
        __syncthreads();
        sums[tid] += v;
        __syncthreads();
    }
    int base = (tid == 0) ? 0 : sums[tid - 1];
    for (int i = lo; i < hi; ++i) {
        rowptr[i] = base;
        cursor[i] = base;
        base += deg[i];
    }
    if (tid == 255) rowptr[Nn] = sums[255];
}

__global__ void fill_kernel(const int* __restrict__ src, const int* __restrict__ dst,
                            int* __restrict__ cursor, int* __restrict__ eidx, int E)
{
    int e = blockIdx.x * blockDim.x + threadIdx.x;
    if (e < E) {
        int d = dst[e];
        int pos = atomicAdd(&cursor[d], 1);
        eidx[pos] = src[e];
    }
}

// ---------------- per-node attention logit coefficients ----------------
__global__ __launch_bounds__(256) void att_kernel(
    const float* __restrict__ h, const float* __restrict__ atts, const float* __restrict__ attd,
    float* __restrict__ a_src, float* __restrict__ a_dst)
{
    const int node = blockIdx.x;
    const int wv = threadIdx.x >> 6;
    const int lane = threadIdx.x & 63;
    const int off = wv * HIDC + 2 * lane;
    float2 hv = *(const float2*)(h + (size_t)node * HC + off);
    float2 sv = *(const float2*)(atts + off);
    float2 dv = *(const float2*)(attd + off);
    float ps = hv.x * sv.x + hv.y * sv.y;
    float pd = hv.x * dv.x + hv.y * dv.y;
#pragma unroll
    for (int o = 32; o >= 1; o >>= 1) {
        ps += __shfl_xor(ps, o);
        pd += __shfl_xor(pd, o);
    }
    if (lane == 0) {
        a_src[node * 4 + wv] = ps;
        a_dst[node * 4 + wv] = pd;
    }
}

// ---------------- gather + segment softmax + aggregate + bias + relu -> f16 ------
__global__ __launch_bounds__(256) void gather_kernel(
    const float* __restrict__ h, const float* __restrict__ a_src, const float* __restrict__ a_dst,
    const int* __restrict__ rowptr, const int* __restrict__ eidx,
    const float* __restrict__ bias, _Float16* __restrict__ out)
{
    const int node = blockIdx.x;
    const int tid = threadIdx.x;
    const int wv = tid >> 6;
    const int lane = tid & 63;
    __shared__ float m_s[HEADS], is_s[HEADS];
    const int beg = rowptr[node];
    const int deg = rowptr[node + 1] - beg;   // real in-edges; +1 virtual self loop
    const float4 ad4 = *(const float4*)(a_dst + (size_t)node * 4);

    if (wv == 0) {
        float mx0 = -1e30f, mx1 = -1e30f, mx2 = -1e30f, mx3 = -1e30f;
        for (int e = lane; e <= deg; e += 64) {
            int s = (e == deg) ? node : eidx[beg + e];
            float4 as4 = *(const float4*)(a_src + (size_t)s * 4);
            float l0 = as4.x + ad4.x; l0 = l0 > 0.f ? l0 : NEG * l0;
            float l1 = as4.y + ad4.y; l1 = l1 > 0.f ? l1 : NEG * l1;
            float l2 = as4.z + ad4.z; l2 = l2 > 0.f ? l2 : NEG * l2;
            float l3 = as4.w + ad4.w; l3 = l3 > 0.f ? l3 : NEG * l3;
            mx0 = fmaxf(mx0, l0); mx1 = fmaxf(mx1, l1);
            mx2 = fmaxf(mx2, l2); mx3 = fmaxf(mx3, l3);
        }
#pragma unroll
        for (int o = 32; o >= 1; o >>= 1) {
            mx0 = fmaxf(mx0, __shfl_xor(mx0, o));
            mx1 = fmaxf(mx1, __shfl_xor(mx1, o));
            mx2 = fmaxf(mx2, __shfl_xor(mx2, o));
            mx3 = fmaxf(mx3, __shfl_xor(mx3, o));
        }
        float s0 = 0.f, s1 = 0.f, s2 = 0.f, s3 = 0.f;
        for (int e = lane; e <= deg; e += 64) {
            int s = (e == deg) ? node : eidx[beg + e];
            float4 as4 = *(const float4*)(a_src + (size_t)s * 4);
            float l0 = as4.x + ad4.x; l0 = l0 > 0.f ? l0 : NEG * l0;
            float l1 = as4.y + ad4.y; l1 = l1 > 0.f ? l1 : NEG * l1;
            float l2 = as4.z + ad4.z; l2 = l2 > 0.f ? l2 : NEG * l2;
            float l3 = as4.w + ad4.w; l3 = l3 > 0.f ? l3 : NEG * l3;
            s0 += __expf(l0 - mx0); s1 += __expf(l1 - mx1);
            s2 += __expf(l2 - mx2); s3 += __expf(l3 - mx3);
        }
#pragma unroll
        for (int o = 32; o >= 1; o >>= 1) {
            s0 += __shfl_xor(s0, o); s1 += __shfl_xor(s1, o);
            s2 += __shfl_xor(s2, o); s3 += __shfl_xor(s3, o);
        }
        if (lane == 0) {
            m_s[0] = mx0; m_s[1] = mx1; m_s[2] = mx2; m_s[3] = mx3;
            is_s[0] = 1.f / s0; is_s[1] = 1.f / s1; is_s[2] = 1.f / s2; is_s[3] = 1.f / s3;
        }
    }
    __syncthreads();

    const float m = m_s[wv];
    const float is = is_s[wv];
    const float ad = (wv == 0) ? ad4.x : (wv == 1) ? ad4.y : (wv == 2) ? ad4.z : ad4.w;
    const int coff = wv * HIDC + 2 * lane;
    float2 acc = make_float2(0.f, 0.f);
    for (int e = 0; e <= deg; ++e) {
        int s = (e == deg) ? node : eidx[beg + e];
        float l = a_src[(size_t)s * 4 + wv] + ad;
        l = l > 0.f ? l : NEG * l;
        float wgt = __expf(l - m) * is;
        float2 hv = *(const float2*)(h + (size_t)s * HC + coff);
        acc.x += wgt * hv.x;
        acc.y += wgt * hv.y;
    }
    float2 bv = *(const float2*)(bias + coff);
    float o0 = acc.x + bv.x; o0 = o0 > 0.f ? o0 : 0.f;
    float o1 = acc.y + bv.y; o1 = o1 > 0.f ? o1 : 0.f;
    _Float16* p = out + (size_t)node * HC + coff;
    p[0] = (_Float16)o0;
    p[1] = (_Float16)o1;
}

extern "C" void kernel_launch(void* const* d_in, const int* in_sizes, int n_in,
                              void* d_out, int out_size, void* d_ws, size_t ws_size,
                              hipStream_t stream)
{
    const float* x   = (const float*)d_in[0];
    const int*   ei  = (const int*)d_in[1];
    const float* W1  = (const float*)d_in[2];
    const float* a1s = (const float*)d_in[3];
    const float* a1d = (const float*)d_in[4];
    const float* b1  = (const float*)d_in[5];
    const float* W2  = (const float*)d_in[6];
    const float* a2s = (const float*)d_in[7];
    const float* a2d = (const float*)d_in[8];
    const float* b2  = (const float*)d_in[9];
    const float* Wfc = (const float*)d_in[10];
    const float* bfc = (const float*)d_in[11];
    float* out = (float*)d_out;

    const int Nn  = in_sizes[0] / 384;       // 50000
    const int E   = in_sizes[1] / 2;         // 500000
    const int IN  = 384;
    const int OUT = in_sizes[11];            // 384
    const int Mp  = ((Nn + 127) / 128) * 128; // 50048

    // workspace layout (256B-aligned chunks)
    uint8_t* p = (uint8_t*)d_ws;
    auto alloc = [&](size_t bytes) {
        uint8_t* r = p;
        p += (bytes + 255) & ~(size_t)255;
        return r;
    };
    _Float16* Ah_x = (_Float16*)alloc((size_t)Mp * IN * 2);   // f16 x, padded rows = poison (finite)
    _Float16* Ah_g = (_Float16*)alloc((size_t)Mp * HC * 2);   // f16 gather outputs
    float* hbuf    = (float*)alloc((size_t)Nn * HC * 4);      // fp32 GEMM out (h)
    _Float16* Wt1  = (_Float16*)alloc((size_t)HC * IN * 2);
    _Float16* Wt2  = (_Float16*)alloc((size_t)HC * HC * 2);
    _Float16* Wt3  = (_Float16*)alloc((size_t)OUT * HC * 2);
    float* a_src   = (float*)alloc((size_t)Nn * 4 * 4);
    float* a_dst   = (float*)alloc((size_t)Nn * 4 * 4);
    int* deg       = (int*)alloc((size_t)Nn * 4);
    int* rowptr    = (int*)alloc((size_t)(Nn + 1) * 4);
    int* cursor    = (int*)alloc((size_t)Nn * 4);
    int* eidx      = (int*)alloc((size_t)E * 4);

    const int* e_src = ei;
    const int* e_dst = ei + E;

    // conversions
    {
        size_t nq = (size_t)Nn * IN / 4;
        convert_x_kernel<<<(nq + 255) / 256, 256, 0, stream>>>(x, Ah_x, nq);
        dim3 gw1((IN + 63) / 64, HC / 4);
        convert_wT_kernel<<<gw1, 256, 0, stream>>>(W1, Wt1, IN, HC);
        dim3 gw2((HC + 63) / 64, HC / 4);
        convert_wT_kernel<<<gw2, 256, 0, stream>>>(W2, Wt2, HC, HC);
        dim3 gw3((HC + 63) / 64, OUT / 4);
        convert_wT_kernel<<<gw3, 256, 0, stream>>>(Wfc, Wt3, HC, OUT);
    }

    // CSR build
    hipMemsetAsync(deg, 0, Nn * sizeof(int), stream);
    const int eb = (E + 255) / 256;
    count_kernel<<<eb, 256, 0, stream>>>(e_dst, deg, E);
    scan_kernel<<<1, 256, 0, stream>>>(deg, rowptr, cursor, Nn);
    fill_kernel<<<eb, 256, 0, stream>>>(e_src, e_dst, cursor, eidx, E);

    const dim3 gg1(HC / 128, Mp / 128);

    // layer 1
    mfma_gemm<<<gg1, 256, 0, stream>>>(Ah_x, Wt1, hbuf, nullptr, Nn, HC, IN);
    att_kernel<<<Nn, 256, 0, stream>>>(hbuf, a1s, a1d, a_src, a_dst);
    gather_kernel<<<Nn, 256, 0, stream>>>(hbuf, a_src, a_dst, rowptr, eidx, b1, Ah_g);

    // layer 2
    mfma_gemm<<<gg1, 256, 0, stream>>>(Ah_g, Wt2, hbuf, nullptr, Nn, HC, HC);
    att_kernel<<<Nn, 256, 0, stream>>>(hbuf, a2s, a2d, a_src, a_dst);
    gather_kernel<<<Nn, 256, 0, stream>>>(hbuf, a_src, a_dst, rowptr, eidx, b2, Ah_g);

    // final FC -> fp32 out
    const dim3 gg3(OUT / 128, Mp / 128);
    mfma_gemm<<<gg3, 256, 0, stream>>>(Ah_g, Wt3, out, bfc, Nn, OUT, HC);
}

// Round 3
// 871.431 us; speedup vs baseline: 1.8037x; 1.1095x over previous
//
#include <hip/hip_runtime.h>
#include <cfloat>
#include <cstdint>

#define HEADS 4
#define HIDC 128
#define HC 512
#define NEG 0.2f

typedef _Float16 half8 __attribute__((ext_vector_type(8)));
typedef _Float16 half2v __attribute__((ext_vector_type(2)));
typedef float floatx4 __attribute__((ext_vector_type(4)));

// ---------------- f16 MFMA GEMM ----------------
// C = A[Mp,K] @ Bt[N,K]^T. 128x128 tile, BK=32, 4 waves 2x2, each 64x64 via
// 4x4 mfma_f32_16x16x32_f16. Staging via global_load_lds width=16.
// Outputs: Ch (f16, layers) or Cf (fp32+bias, final FC).
// If atts != null (N==512): fuse a_src/a_dst per-head dot into epilogue
// (blockIdx.x == head since cols-per-block == HIDC == 128).
__global__ __launch_bounds__(256) void mfma_gemm(
    const _Float16* __restrict__ A,   // [Mp][K]
    const _Float16* __restrict__ Bt,  // [N][K]
    _Float16* __restrict__ Ch,        // [Mp][N] f16 out (or null)
    float* __restrict__ Cf,           // [M][N] fp32 out (or null)
    const float* __restrict__ bias,   // [N] (with Cf) or null
    const float* __restrict__ atts,   // [HEADS][128] or null
    const float* __restrict__ attd,
    float* __restrict__ a_src,        // [M][4]
    float* __restrict__ a_dst,
    int M, int N, int K)
{
    __shared__ __align__(16) _Float16 As[128 * 32];
    __shared__ __align__(16) _Float16 Bs[128 * 32];

    const int tid = threadIdx.x;
    const int w = tid >> 6;
    const int lane = tid & 63;
    const int wr = (w >> 1) * 64;
    const int wc = (w & 1) * 64;

    const int rowBase = blockIdx.y * 128;
    const int colBase = blockIdx.x * 128;

    const int sRow0 = (w * 2 + 0) * 16 + (lane >> 2);
    const int sRow1 = (w * 2 + 1) * 16 + (lane >> 2);
    const int sCol = (lane & 3) * 8;

    const _Float16* gA0 = A + (size_t)(rowBase + sRow0) * K + sCol;
    const _Float16* gA1 = A + (size_t)(rowBase + sRow1) * K + sCol;
    const _Float16* gB0 = Bt + (size_t)(colBase + sRow0) * K + sCol;
    const _Float16* gB1 = Bt + (size_t)(colBase + sRow1) * K + sCol;

    _Float16* lA0 = &As[(w * 2 + 0) * 512];
    _Float16* lA1 = &As[(w * 2 + 1) * 512];
    _Float16* lB0 = &Bs[(w * 2 + 0) * 512];
    _Float16* lB1 = &Bs[(w * 2 + 1) * 512];

    floatx4 acc[4][4];
#pragma unroll
    for (int i = 0; i < 4; i++)
#pragma unroll
        for (int j = 0; j < 4; j++) acc[i][j] = {0.f, 0.f, 0.f, 0.f};

    const int q = lane >> 4;
    const int l16 = lane & 15;

    for (int k0 = 0; k0 < K; k0 += 32) {
        __builtin_amdgcn_global_load_lds(
            (const __attribute__((address_space(1))) unsigned int*)(gA0 + k0),
            (__attribute__((address_space(3))) unsigned int*)lA0, 16, 0, 0);
        __builtin_amdgcn_global_load_lds(
            (const __attribute__((address_space(1))) unsigned int*)(gA1 + k0),
            (__attribute__((address_space(3))) unsigned int*)lA1, 16, 0, 0);
        __builtin_amdgcn_global_load_lds(
            (const __attribute__((address_space(1))) unsigned int*)(gB0 + k0),
            (__attribute__((address_space(3))) unsigned int*)lB0, 16, 0, 0);
        __builtin_amdgcn_global_load_lds(
            (const __attribute__((address_space(1))) unsigned int*)(gB1 + k0),
            (__attribute__((address_space(3))) unsigned int*)lB1, 16, 0, 0);
        __syncthreads();

        half8 af[4], bf[4];
#pragma unroll
        for (int i = 0; i < 4; i++)
            af[i] = *(const half8*)&As[(wr + i * 16 + l16) * 32 + q * 8];
#pragma unroll
        for (int j = 0; j < 4; j++)
            bf[j] = *(const half8*)&Bs[(wc + j * 16 + l16) * 32 + q * 8];
#pragma unroll
        for (int i = 0; i < 4; i++)
#pragma unroll
            for (int j = 0; j < 4; j++)
                acc[i][j] = __builtin_amdgcn_mfma_f32_16x16x32_f16(af[i], bf[j], acc[i][j], 0, 0, 0);
        __syncthreads();
    }

    // ---- C stores (C/D layout: col=l16, row=q*4+r) ----
    if (Ch) {
#pragma unroll
        for (int i = 0; i < 4; i++)
#pragma unroll
            for (int j = 0; j < 4; j++) {
                const int col = colBase + wc + j * 16 + l16;
#pragma unroll
                for (int r = 0; r < 4; r++) {
                    const int row = rowBase + wr + i * 16 + q * 4 + r;
                    if (row < M) Ch[(size_t)row * N + col] = (_Float16)acc[i][j][r];
                }
            }
    }
    if (Cf) {
#pragma unroll
        for (int i = 0; i < 4; i++)
#pragma unroll
            for (int j = 0; j < 4; j++) {
                const int col = colBase + wc + j * 16 + l16;
                const float bb = bias ? bias[col] : 0.f;
#pragma unroll
                for (int r = 0; r < 4; r++) {
                    const int row = rowBase + wr + i * 16 + q * 4 + r;
                    if (row < M) Cf[(size_t)row * N + col] = acc[i][j][r] + bb;
                }
            }
    }

    // ---- fused attention coefficients (layers only) ----
    if (atts) {
        // reuse As LDS (all waves past last __syncthreads of K loop)
        float* ps = (float*)As;        // [2][128]
        float* pd = ps + 256;          // [2][128]
        const int head = blockIdx.x;
        float as[4], ad[4];
#pragma unroll
        for (int j = 0; j < 4; j++) {
            const int cl = wc + j * 16 + l16;
            as[j] = atts[head * HIDC + cl];
            ad[j] = attd[head * HIDC + cl];
        }
#pragma unroll
        for (int i = 0; i < 4; i++) {
#pragma unroll
            for (int r = 0; r < 4; r++) {
                float s_ = acc[i][0][r] * as[0] + acc[i][1][r] * as[1]
                         + acc[i][2][r] * as[2] + acc[i][3][r] * as[3];
                float d_ = acc[i][0][r] * ad[0] + acc[i][1][r] * ad[1]
                         + acc[i][2][r] * ad[2] + acc[i][3][r] * ad[3];
#pragma unroll
                for (int mk = 1; mk <= 8; mk <<= 1) {
                    s_ += __shfl_xor(s_, mk);
                    d_ += __shfl_xor(d_, mk);
                }
                if (l16 == 0) {
                    const int rloc = wr + i * 16 + q * 4 + r;
                    ps[(wc >> 6) * 128 + rloc] = s_;
                    pd[(wc >> 6) * 128 + rloc] = d_;
                }
            }
        }
        __syncthreads();
        if (tid < 128) {
            const int row = rowBase + tid;
            if (row < M) {
                a_src[(size_t)row * 4 + head] = ps[tid] + ps[128 + tid];
                a_dst[(size_t)row * 4 + head] = pd[tid] + pd[128 + tid];
            }
        }
    }
}

// ---------------- dtype conversion ----------------
__global__ void convert_x_kernel(const float* __restrict__ x, _Float16* __restrict__ o, size_t nquads)
{
    size_t i = (size_t)blockIdx.x * blockDim.x + threadIdx.x;
    if (i < nquads) {
        float4 v = *(const float4*)(x + i * 4);
        _Float16* p = o + i * 4;
        p[0] = (_Float16)v.x; p[1] = (_Float16)v.y;
        p[2] = (_Float16)v.z; p[3] = (_Float16)v.w;
    }
}

// W[k][n] (fp32) -> Wt[n][k] (f16)
__global__ void convert_wT_kernel(const float* __restrict__ W, _Float16* __restrict__ Wt, int K, int N)
{
    int k = blockIdx.x * 64 + (threadIdx.x & 63);
    int n = blockIdx.y * 4 + (threadIdx.x >> 6);
    if (k < K && n < N) Wt[(size_t)n * K + k] = (_Float16)W[(size_t)k * N + n];
}

// ---------------- CSR build (by dst) ----------------
__global__ void count_kernel(const int* __restrict__ dst, int* __restrict__ deg, int E)
{
    int e = blockIdx.x * blockDim.x + threadIdx.x;
    if (e < E) atomicAdd(&deg[dst[e]], 1);
}

__global__ __launch_bounds__(256) void scan_kernel(
    const int* __restrict__ deg, int* __restrict__ rowptr, int* __restrict__ cursor, int Nn)
{
    __shared__ int sums[256];
    const int tid = threadIdx.x;
    const int chunk = (Nn + 255) >> 8;
    const int lo = tid * chunk;
    const int hi = min(lo + chunk, Nn);
    int s = 0;
    for (int i = lo; i < hi; ++i) s += deg[i];
    sums[tid] = s;
    __syncthreads();
    for (int off = 1; off < 256; off <<= 1) {
        int v = (tid >= off) ? sums[tid - off] : 0;
        __syncthreads();
        sums[tid] += v;
        __syncthreads();
    }
    int base = (tid == 0) ? 0 : sums[tid - 1];
    for (int i = lo; i < hi; ++i) {
        rowptr[i] = base;
        cursor[i] = base;
        base += deg[i];
    }
    if (tid == 255) rowptr[Nn] = sums[255];
}

__global__ void fill_kernel(const int* __restrict__ src, const int* __restrict__ dst,
                            int* __restrict__ cursor, int* __restrict__ eidx, int E)
{
    int e = blockIdx.x * blockDim.x + threadIdx.x;
    if (e < E) {
        int d = dst[e];
        int pos = atomicAdd(&cursor[d], 1);
        eidx[pos] = src[e];
    }
}

// ---------------- gather: softmax over in-edges + aggregate + bias + relu -> f16 --
// h is f16 now. One block per node; wave w = head w, 2 channels/lane.
__global__ __launch_bounds__(256) void gather_kernel(
    const _Float16* __restrict__ h, const float* __restrict__ a_src, const float* __restrict__ a_dst,
    const int* __restrict__ rowptr, const int* __restrict__ eidx,
    const float* __restrict__ bias, _Float16* __restrict__ out)
{
    const int node = blockIdx.x;
    const int tid = threadIdx.x;
    const int wv = tid >> 6;
    const int lane = tid & 63;
    __shared__ float m_s[HEADS], is_s[HEADS];
    const int beg = rowptr[node];
    const int deg = rowptr[node + 1] - beg;   // real in-edges; +1 virtual self loop
    const float4 ad4 = *(const float4*)(a_dst + (size_t)node * 4);

    if (wv == 0) {
        float mx0 = -1e30f, mx1 = -1e30f, mx2 = -1e30f, mx3 = -1e30f;
        for (int e = lane; e <= deg; e += 64) {
            int s = (e == deg) ? node : eidx[beg + e];
            float4 as4 = *(const float4*)(a_src + (size_t)s * 4);
            float l0 = as4.x + ad4.x; l0 = l0 > 0.f ? l0 : NEG * l0;
            float l1 = as4.y + ad4.y; l1 = l1 > 0.f ? l1 : NEG * l1;
            float l2 = as4.z + ad4.z; l2 = l2 > 0.f ? l2 : NEG * l2;
            float l3 = as4.w + ad4.w; l3 = l3 > 0.f ? l3 : NEG * l3;
            mx0 = fmaxf(mx0, l0); mx1 = fmaxf(mx1, l1);
            mx2 = fmaxf(mx2, l2); mx3 = fmaxf(mx3, l3);
        }
#pragma unroll
        for (int o = 32; o >= 1; o >>= 1) {
            mx0 = fmaxf(mx0, __shfl_xor(mx0, o));
            mx1 = fmaxf(mx1, __shfl_xor(mx1, o));
            mx2 = fmaxf(mx2, __shfl_xor(mx2, o));
            mx3 = fmaxf(mx3, __shfl_xor(mx3, o));
        }
        float s0 = 0.f, s1 = 0.f, s2 = 0.f, s3 = 0.f;
        for (int e = lane; e <= deg; e += 64) {
            int s = (e == deg) ? node : eidx[beg + e];
            float4 as4 = *(const float4*)(a_src + (size_t)s * 4);
            float l0 = as4.x + ad4.x; l0 = l0 > 0.f ? l0 : NEG * l0;
            float l1 = as4.y + ad4.y; l1 = l1 > 0.f ? l1 : NEG * l1;
            float l2 = as4.z + ad4.z; l2 = l2 > 0.f ? l2 : NEG * l2;
            float l3 = as4.w + ad4.w; l3 = l3 > 0.f ? l3 : NEG * l3;
            s0 += __expf(l0 - mx0); s1 += __expf(l1 - mx1);
            s2 += __expf(l2 - mx2); s3 += __expf(l3 - mx3);
        }
#pragma unroll
        for (int o = 32; o >= 1; o >>= 1) {
            s0 += __shfl_xor(s0, o); s1 += __shfl_xor(s1, o);
            s2 += __shfl_xor(s2, o); s3 += __shfl_xor(s3, o);
        }
        if (lane == 0) {
            m_s[0] = mx0; m_s[1] = mx1; m_s[2] = mx2; m_s[3] = mx3;
            is_s[0] = 1.f / s0; is_s[1] = 1.f / s1; is_s[2] = 1.f / s2; is_s[3] = 1.f / s3;
        }
    }
    __syncthreads();

    const float m = m_s[wv];
    const float is = is_s[wv];
    const float ad = (wv == 0) ? ad4.x : (wv == 1) ? ad4.y : (wv == 2) ? ad4.z : ad4.w;
    const int coff = wv * HIDC + 2 * lane;
    float2 acc = make_float2(0.f, 0.f);
    for (int e = 0; e <= deg; ++e) {
        int s = (e == deg) ? node : eidx[beg + e];
        float l = a_src[(size_t)s * 4 + wv] + ad;
        l = l > 0.f ? l : NEG * l;
        float wgt = __expf(l - m) * is;
        half2v hv = *(const half2v*)(h + (size_t)s * HC + coff);
        acc.x += wgt * (float)hv.x;
        acc.y += wgt * (float)hv.y;
    }
    float2 bv = *(const float2*)(bias + coff);
    float o0 = acc.x + bv.x; o0 = o0 > 0.f ? o0 : 0.f;
    float o1 = acc.y + bv.y; o1 = o1 > 0.f ? o1 : 0.f;
    half2v ov; ov.x = (_Float16)o0; ov.y = (_Float16)o1;
    *(half2v*)(out + (size_t)node * HC + coff) = ov;
}

extern "C" void kernel_launch(void* const* d_in, const int* in_sizes, int n_in,
                              void* d_out, int out_size, void* d_ws, size_t ws_size,
                              hipStream_t stream)
{
    const float* x   = (const float*)d_in[0];
    const int*   ei  = (const int*)d_in[1];
    const float* W1  = (const float*)d_in[2];
    const float* a1s = (const float*)d_in[3];
    const float* a1d = (const float*)d_in[4];
    const float* b1  = (const float*)d_in[5];
    const float* W2  = (const float*)d_in[6];
    const float* a2s = (const float*)d_in[7];
    const float* a2d = (const float*)d_in[8];
    const float* b2  = (const float*)d_in[9];
    const float* Wfc = (const float*)d_in[10];
    const float* bfc = (const float*)d_in[11];
    float* out = (float*)d_out;

    const int Nn  = in_sizes[0] / 384;        // 50000
    const int E   = in_sizes[1] / 2;          // 500000
    const int IN  = 384;
    const int OUT = in_sizes[11];             // 384
    const int Mp  = ((Nn + 127) / 128) * 128; // 50048

    uint8_t* p = (uint8_t*)d_ws;
    auto alloc = [&](size_t bytes) {
        uint8_t* r = p;
        p += (bytes + 255) & ~(size_t)255;
        return r;
    };
    _Float16* Ah_x = (_Float16*)alloc((size_t)Mp * IN * 2);   // f16 x
    _Float16* Ah_g = (_Float16*)alloc((size_t)Mp * HC * 2);   // gather outputs (GEMM input)
    _Float16* Hh   = (_Float16*)alloc((size_t)Mp * HC * 2);   // GEMM output h (f16)
    _Float16* Wt1  = (_Float16*)alloc((size_t)HC * IN * 2);
    _Float16* Wt2  = (_Float16*)alloc((size_t)HC * HC * 2);
    _Float16* Wt3  = (_Float16*)alloc((size_t)OUT * HC * 2);
    float* a_src   = (float*)alloc((size_t)Nn * 4 * 4);
    float* a_dst   = (float*)alloc((size_t)Nn * 4 * 4);
    int* deg       = (int*)alloc((size_t)Nn * 4);
    int* rowptr    = (int*)alloc((size_t)(Nn + 1) * 4);
    int* cursor    = (int*)alloc((size_t)Nn * 4);
    int* eidx      = (int*)alloc((size_t)E * 4);

    const int* e_src = ei;
    const int* e_dst = ei + E;

    // conversions
    {
        size_t nq = (size_t)Nn * IN / 4;
        convert_x_kernel<<<(nq + 255) / 256, 256, 0, stream>>>(x, Ah_x, nq);
        dim3 gw1((IN + 63) / 64, HC / 4);
        convert_wT_kernel<<<gw1, 256, 0, stream>>>(W1, Wt1, IN, HC);
        dim3 gw2((HC + 63) / 64, HC / 4);
        convert_wT_kernel<<<gw2, 256, 0, stream>>>(W2, Wt2, HC, HC);
        dim3 gw3((HC + 63) / 64, OUT / 4);
        convert_wT_kernel<<<gw3, 256, 0, stream>>>(Wfc, Wt3, HC, OUT);
    }

    // CSR build
    hipMemsetAsync(deg, 0, Nn * sizeof(int), stream);
    const int eb = (E + 255) / 256;
    count_kernel<<<eb, 256, 0, stream>>>(e_dst, deg, E);
    scan_kernel<<<1, 256, 0, stream>>>(deg, rowptr, cursor, Nn);
    fill_kernel<<<eb, 256, 0, stream>>>(e_src, e_dst, cursor, eidx, E);

    const dim3 gg1(HC / 128, Mp / 128);

    // layer 1: GEMM (f16 out) + fused att
    mfma_gemm<<<gg1, 256, 0, stream>>>(Ah_x, Wt1, Hh, nullptr, nullptr,
                                       a1s, a1d, a_src, a_dst, Nn, HC, IN);
    gather_kernel<<<Nn, 256, 0, stream>>>(Hh, a_src, a_dst, rowptr, eidx, b1, Ah_g);

    // layer 2
    mfma_gemm<<<gg1, 256, 0, stream>>>(Ah_g, Wt2, Hh, nullptr, nullptr,
                                       a2s, a2d, a_src, a_dst, Nn, HC, HC);
    gather_kernel<<<Nn, 256, 0, stream>>>(Hh, a_src, a_dst, rowptr, eidx, b2, Ah_g);

    // final FC -> fp32 out
    const dim3 gg3(OUT / 128, Mp / 128);
    mfma_gemm<<<gg3, 256, 0, stream>>>(Ah_g, Wt3, nullptr, out, bfc,
                                       nullptr, nullptr, nullptr, nullptr, Nn, OUT, HC);
}

// Round 4
// 708.780 us; speedup vs baseline: 2.2176x; 1.2295x over previous
//
#include <hip/hip_runtime.h>
#include <cfloat>
#include <cstdint>

#define HEADS 4
#define HIDC 128
#define HC 512
#define NEG 0.2f

typedef _Float16 half8 __attribute__((ext_vector_type(8)));
typedef _Float16 half2v __attribute__((ext_vector_type(2)));
typedef float floatx4 __attribute__((ext_vector_type(4)));

// ---------------- f16 MFMA GEMM ----------------
// C = A[Mp,K] @ Bt[N,K]^T. 128x128 tile, BK=32, 4 waves 2x2, each 64x64 via
// 4x4 mfma_f32_16x16x32_f16. Staging via global_load_lds width=16.
// Outputs: Ch (f16, layers) or Cf (fp32+bias, final FC).
// If atts != null (N==512): fuse a_src/a_dst per-head dot into epilogue
// (blockIdx.x == head since cols-per-block == HIDC == 128).
__global__ __launch_bounds__(256) void mfma_gemm(
    const _Float16* __restrict__ A,   // [Mp][K]
    const _Float16* __restrict__ Bt,  // [N][K]
    _Float16* __restrict__ Ch,        // [Mp][N] f16 out (or null)
    float* __restrict__ Cf,           // [M][N] fp32 out (or null)
    const float* __restrict__ bias,   // [N] (with Cf) or null
    const float* __restrict__ atts,   // [HEADS][128] or null
    const float* __restrict__ attd,
    float* __restrict__ a_src,        // [M][4]
    float* __restrict__ a_dst,
    int M, int N, int K)
{
    __shared__ __align__(16) _Float16 As[128 * 32];
    __shared__ __align__(16) _Float16 Bs[128 * 32];

    const int tid = threadIdx.x;
    const int w = tid >> 6;
    const int lane = tid & 63;
    const int wr = (w >> 1) * 64;
    const int wc = (w & 1) * 64;

    const int rowBase = blockIdx.y * 128;
    const int colBase = blockIdx.x * 128;

    const int sRow0 = (w * 2 + 0) * 16 + (lane >> 2);
    const int sRow1 = (w * 2 + 1) * 16 + (lane >> 2);
    const int sCol = (lane & 3) * 8;

    const _Float16* gA0 = A + (size_t)(rowBase + sRow0) * K + sCol;
    const _Float16* gA1 = A + (size_t)(rowBase + sRow1) * K + sCol;
    const _Float16* gB0 = Bt + (size_t)(colBase + sRow0) * K + sCol;
    const _Float16* gB1 = Bt + (size_t)(colBase + sRow1) * K + sCol;

    _Float16* lA0 = &As[(w * 2 + 0) * 512];
    _Float16* lA1 = &As[(w * 2 + 1) * 512];
    _Float16* lB0 = &Bs[(w * 2 + 0) * 512];
    _Float16* lB1 = &Bs[(w * 2 + 1) * 512];

    floatx4 acc[4][4];
#pragma unroll
    for (int i = 0; i < 4; i++)
#pragma unroll
        for (int j = 0; j < 4; j++) acc[i][j] = {0.f, 0.f, 0.f, 0.f};

    const int q = lane >> 4;
    const int l16 = lane & 15;

    for (int k0 = 0; k0 < K; k0 += 32) {
        __builtin_amdgcn_global_load_lds(
            (const __attribute__((address_space(1))) unsigned int*)(gA0 + k0),
            (__attribute__((address_space(3))) unsigned int*)lA0, 16, 0, 0);
        __builtin_amdgcn_global_load_lds(
            (const __attribute__((address_space(1))) unsigned int*)(gA1 + k0),
            (__attribute__((address_space(3))) unsigned int*)lA1, 16, 0, 0);
        __builtin_amdgcn_global_load_lds(
            (const __attribute__((address_space(1))) unsigned int*)(gB0 + k0),
            (__attribute__((address_space(3))) unsigned int*)lB0, 16, 0, 0);
        __builtin_amdgcn_global_load_lds(
            (const __attribute__((address_space(1))) unsigned int*)(gB1 + k0),
            (__attribute__((address_space(3))) unsigned int*)lB1, 16, 0, 0);
        __syncthreads();

        half8 af[4], bf[4];
#pragma unroll
        for (int i = 0; i < 4; i++)
            af[i] = *(const half8*)&As[(wr + i * 16 + l16) * 32 + q * 8];
#pragma unroll
        for (int j = 0; j < 4; j++)
            bf[j] = *(const half8*)&Bs[(wc + j * 16 + l16) * 32 + q * 8];
#pragma unroll
        for (int i = 0; i < 4; i++)
#pragma unroll
            for (int j = 0; j < 4; j++)
                acc[i][j] = __builtin_amdgcn_mfma_f32_16x16x32_f16(af[i], bf[j], acc[i][j], 0, 0, 0);
        __syncthreads();
    }

    // ---- C stores (C/D layout: col=l16, row=q*4+r) ----
    if (Ch) {
#pragma unroll
        for (int i = 0; i < 4; i++)
#pragma unroll
            for (int j = 0; j < 4; j++) {
                const int col = colBase + wc + j * 16 + l16;
#pragma unroll
                for (int r = 0; r < 4; r++) {
                    const int row = rowBase + wr + i * 16 + q * 4 + r;
                    if (row < M) Ch[(size_t)row * N + col] = (_Float16)acc[i][j][r];
                }
            }
    }
    if (Cf) {
#pragma unroll
        for (int i = 0; i < 4; i++)
#pragma unroll
            for (int j = 0; j < 4; j++) {
                const int col = colBase + wc + j * 16 + l16;
                const float bb = bias ? bias[col] : 0.f;
#pragma unroll
                for (int r = 0; r < 4; r++) {
                    const int row = rowBase + wr + i * 16 + q * 4 + r;
                    if (row < M) Cf[(size_t)row * N + col] = acc[i][j][r] + bb;
                }
            }
    }

    // ---- fused attention coefficients (layers only) ----
    if (atts) {
        float* ps = (float*)As;        // [2][128]
        float* pd = ps + 256;          // [2][128]
        const int head = blockIdx.x;
        float as[4], ad[4];
#pragma unroll
        for (int j = 0; j < 4; j++) {
            const int cl = wc + j * 16 + l16;
            as[j] = atts[head * HIDC + cl];
            ad[j] = attd[head * HIDC + cl];
        }
#pragma unroll
        for (int i = 0; i < 4; i++) {
#pragma unroll
            for (int r = 0; r < 4; r++) {
                float s_ = acc[i][0][r] * as[0] + acc[i][1][r] * as[1]
                         + acc[i][2][r] * as[2] + acc[i][3][r] * as[3];
                float d_ = acc[i][0][r] * ad[0] + acc[i][1][r] * ad[1]
                         + acc[i][2][r] * ad[2] + acc[i][3][r] * ad[3];
#pragma unroll
                for (int mk = 1; mk <= 8; mk <<= 1) {
                    s_ += __shfl_xor(s_, mk);
                    d_ += __shfl_xor(d_, mk);
                }
                if (l16 == 0) {
                    const int rloc = wr + i * 16 + q * 4 + r;
                    ps[(wc >> 6) * 128 + rloc] = s_;
                    pd[(wc >> 6) * 128 + rloc] = d_;
                }
            }
        }
        __syncthreads();
        if (tid < 128) {
            const int row = rowBase + tid;
            if (row < M) {
                a_src[(size_t)row * 4 + head] = ps[tid] + ps[128 + tid];
                a_dst[(size_t)row * 4 + head] = pd[tid] + pd[128 + tid];
            }
        }
    }
}

// ---------------- dtype conversion ----------------
__global__ void convert_x_kernel(const float* __restrict__ x, _Float16* __restrict__ o, size_t nquads)
{
    size_t i = (size_t)blockIdx.x * blockDim.x + threadIdx.x;
    if (i < nquads) {
        float4 v = *(const float4*)(x + i * 4);
        _Float16* p = o + i * 4;
        p[0] = (_Float16)v.x; p[1] = (_Float16)v.y;
        p[2] = (_Float16)v.z; p[3] = (_Float16)v.w;
    }
}

// W[k][n] (fp32) -> Wt[n][k] (f16)
__global__ void convert_wT_kernel(const float* __restrict__ W, _Float16* __restrict__ Wt, int K, int N)
{
    int k = blockIdx.x * 64 + (threadIdx.x & 63);
    int n = blockIdx.y * 4 + (threadIdx.x >> 6);
    if (k < K && n < N) Wt[(size_t)n * K + k] = (_Float16)W[(size_t)k * N + n];
}

// ---------------- CSR build (by dst) ----------------
__global__ void count_kernel(const int* __restrict__ dst, int* __restrict__ deg, int E)
{
    int e = blockIdx.x * blockDim.x + threadIdx.x;
    if (e < E) atomicAdd(&deg[dst[e]], 1);
}

__global__ __launch_bounds__(256) void scan_kernel(
    const int* __restrict__ deg, int* __restrict__ rowptr, int* __restrict__ cursor, int Nn)
{
    __shared__ int sums[256];
    const int tid = threadIdx.x;
    const int chunk = (Nn + 255) >> 8;
    const int lo = tid * chunk;
    const int hi = min(lo + chunk, Nn);
    int s = 0;
    for (int i = lo; i < hi; ++i) s += deg[i];
    sums[tid] = s;
    __syncthreads();
    for (int off = 1; off < 256; off <<= 1) {
        int v = (tid >= off) ? sums[tid - off] : 0;
        __syncthreads();
        sums[tid] += v;
        __syncthreads();
    }
    int base = (tid == 0) ? 0 : sums[tid - 1];
    for (int i = lo; i < hi; ++i) {
        rowptr[i] = base;
        cursor[i] = base;
        base += deg[i];
    }
    if (tid == 255) rowptr[Nn] = sums[255];
}

__global__ void fill_kernel(const int* __restrict__ src, const int* __restrict__ dst,
                            int* __restrict__ cursor, int* __restrict__ eidx, int E)
{
    int e = blockIdx.x * blockDim.x + threadIdx.x;
    if (e < E) {
        int d = dst[e];
        int pos = atomicAdd(&cursor[d], 1);
        eidx[pos] = src[e];
    }
}

// ---------------- gather v2: edge-parallel weights + full-row waves ----------------
// One block per node. Phase A: thread t = edge t computes exp(leaky(logit)) for all
// 4 heads into LDS (no max pass; normalize at the end). Phase B: the 4 waves split
// the edge list; each wave loads the FULL 1KB h row (half8/lane) and accumulates
// weighted partials. Cross-wave reduce, *1/sum, +bias, relu, f16 store.
__global__ __launch_bounds__(256) void gather_kernel(
    const _Float16* __restrict__ h, const float* __restrict__ a_src, const float* __restrict__ a_dst,
    const int* __restrict__ rowptr, const int* __restrict__ eidx,
    const float* __restrict__ bias, _Float16* __restrict__ out)
{
    const int node = blockIdx.x;
    const int tid = threadIdx.x;
    const int wv = tid >> 6;
    const int lane = tid & 63;

    __shared__ __align__(16) float wgt[256][4];
    __shared__ int sidx[256];
    __shared__ float accs[4][HC];
    __shared__ float part[4][4];

    const int beg = rowptr[node];
    const int total = rowptr[node + 1] - beg + 1;   // + virtual self-loop
    const float4 ad4 = *(const float4*)(a_dst + (size_t)node * 4);

    float acc[8];
#pragma unroll
    for (int i = 0; i < 8; i++) acc[i] = 0.f;
    float4 dsum = make_float4(0.f, 0.f, 0.f, 0.f);

    const int hd = lane >> 4;   // head owned by this lane's channels in phase B
    const _Float16* hrow_base = h + (size_t)lane * 8;

    for (int off = 0; off < total; off += 256) {
        const int clen = min(total - off, 256);
        if (tid < clen) {
            const int e = off + tid;
            const int s = (e == total - 1) ? node : eidx[beg + e];
            sidx[tid] = s;
            float4 as4 = *(const float4*)(a_src + (size_t)s * 4);
            float l0 = as4.x + ad4.x; l0 = l0 > 0.f ? l0 : NEG * l0;
            float l1 = as4.y + ad4.y; l1 = l1 > 0.f ? l1 : NEG * l1;
            float l2 = as4.z + ad4.z; l2 = l2 > 0.f ? l2 : NEG * l2;
            float l3 = as4.w + ad4.w; l3 = l3 > 0.f ? l3 : NEG * l3;
            float4 w4 = make_float4(__expf(l0), __expf(l1), __expf(l2), __expf(l3));
            *(float4*)&wgt[tid][0] = w4;
            dsum.x += w4.x; dsum.y += w4.y; dsum.z += w4.z; dsum.w += w4.w;
        }
        __syncthreads();
        for (int e = wv; e < clen; e += 4) {
            const float w = wgt[e][hd];
            const int s = sidx[e];
            half8 hv = *(const half8*)(hrow_base + (size_t)s * HC);
#pragma unroll
            for (int i = 0; i < 8; i++) acc[i] += w * (float)hv[i];
        }
        __syncthreads();
    }

    // block-reduce denominators (per head)
#pragma unroll
    for (int o = 32; o >= 1; o >>= 1) {
        dsum.x += __shfl_xor(dsum.x, o);
        dsum.y += __shfl_xor(dsum.y, o);
        dsum.z += __shfl_xor(dsum.z, o);
        dsum.w += __shfl_xor(dsum.w, o);
    }
    if (lane == 0) {
        part[wv][0] = dsum.x; part[wv][1] = dsum.y;
        part[wv][2] = dsum.z; part[wv][3] = dsum.w;
    }
    // dump per-wave partial accumulators
    float* ap = &accs[wv][lane * 8];
#pragma unroll
    for (int i = 0; i < 8; i++) ap[i] = acc[i];
    __syncthreads();

    // final: thread t owns channels 2t, 2t+1 (same head)
    const int ch = tid * 2;
    const int head = tid >> 6;
    const float is = 1.f / (part[0][head] + part[1][head] + part[2][head] + part[3][head]);
    float t0 = accs[0][ch] + accs[1][ch] + accs[2][ch] + accs[3][ch];
    float t1 = accs[0][ch + 1] + accs[1][ch + 1] + accs[2][ch + 1] + accs[3][ch + 1];
    float2 bv = *(const float2*)(bias + ch);
    float o0 = t0 * is + bv.x; o0 = o0 > 0.f ? o0 : 0.f;
    float o1 = t1 * is + bv.y; o1 = o1 > 0.f ? o1 : 0.f;
    half2v ov; ov.x = (_Float16)o0; ov.y = (_Float16)o1;
    *(half2v*)(out + (size_t)node * HC + ch) = ov;
}

extern "C" void kernel_launch(void* const* d_in, const int* in_sizes, int n_in,
                              void* d_out, int out_size, void* d_ws, size_t ws_size,
                              hipStream_t stream)
{
    const float* x   = (const float*)d_in[0];
    const int*   ei  = (const int*)d_in[1];
    const float* W1  = (const float*)d_in[2];
    const float* a1s = (const float*)d_in[3];
    const float* a1d = (const float*)d_in[4];
    const float* b1  = (const float*)d_in[5];
    const float* W2  = (const float*)d_in[6];
    const float* a2s = (const float*)d_in[7];
    const float* a2d = (const float*)d_in[8];
    const float* b2  = (const float*)d_in[9];
    const float* Wfc = (const float*)d_in[10];
    const float* bfc = (const float*)d_in[11];
    float* out = (float*)d_out;

    const int Nn  = in_sizes[0] / 384;        // 50000
    const int E   = in_sizes[1] / 2;          // 500000
    const int IN  = 384;
    const int OUT = in_sizes[11];             // 384
    const int Mp  = ((Nn + 127) / 128) * 128; // 50048

    uint8_t* p = (uint8_t*)d_ws;
    auto alloc = [&](size_t bytes) {
        uint8_t* r = p;
        p += (bytes + 255) & ~(size_t)255;
        return r;
    };
    _Float16* Ah_x = (_Float16*)alloc((size_t)Mp * IN * 2);   // f16 x
    _Float16* Ah_g = (_Float16*)alloc((size_t)Mp * HC * 2);   // gather outputs (GEMM input)
    _Float16* Hh   = (_Float16*)alloc((size_t)Mp * HC * 2);   // GEMM output h (f16)
    _Float16* Wt1  = (_Float16*)alloc((size_t)HC * IN * 2);
    _Float16* Wt2  = (_Float16*)alloc((size_t)HC * HC * 2);
    _Float16* Wt3  = (_Float16*)alloc((size_t)OUT * HC * 2);
    float* a_src   = (float*)alloc((size_t)Nn * 4 * 4);
    float* a_dst   = (float*)alloc((size_t)Nn * 4 * 4);
    int* deg       = (int*)alloc((size_t)Nn * 4);
    int* rowptr    = (int*)alloc((size_t)(Nn + 1) * 4);
    int* cursor    = (int*)alloc((size_t)Nn * 4);
    int* eidx      = (int*)alloc((size_t)E * 4);

    const int* e_src = ei;
    const int* e_dst = ei + E;

    // conversions
    {
        size_t nq = (size_t)Nn * IN / 4;
        convert_x_kernel<<<(nq + 255) / 256, 256, 0, stream>>>(x, Ah_x, nq);
        dim3 gw1((IN + 63) / 64, HC / 4);
        convert_wT_kernel<<<gw1, 256, 0, stream>>>(W1, Wt1, IN, HC);
        dim3 gw2((HC + 63) / 64, HC / 4);
        convert_wT_kernel<<<gw2, 256, 0, stream>>>(W2, Wt2, HC, HC);
        dim3 gw3((HC + 63) / 64, OUT / 4);
        convert_wT_kernel<<<gw3, 256, 0, stream>>>(Wfc, Wt3, HC, OUT);
    }

    // CSR build
    hipMemsetAsync(deg, 0, Nn * sizeof(int), stream);
    const int eb = (E + 255) / 256;
    count_kernel<<<eb, 256, 0, stream>>>(e_dst, deg, E);
    scan_kernel<<<1, 256, 0, stream>>>(deg, rowptr, cursor, Nn);
    fill_kernel<<<eb, 256, 0, stream>>>(e_src, e_dst, cursor, eidx, E);

    const dim3 gg1(HC / 128, Mp / 128);

    // layer 1: GEMM (f16 out) + fused att
    mfma_gemm<<<gg1, 256, 0, stream>>>(Ah_x, Wt1, Hh, nullptr, nullptr,
                                       a1s, a1d, a_src, a_dst, Nn, HC, IN);
    gather_kernel<<<Nn, 256, 0, stream>>>(Hh, a_src, a_dst, rowptr, eidx, b1, Ah_g);

    // layer 2
    mfma_gemm<<<gg1, 256, 0, stream>>>(Ah_g, Wt2, Hh, nullptr, nullptr,
                                       a2s, a2d, a_src, a_dst, Nn, HC, HC);
    gather_kernel<<<Nn, 256, 0, stream>>>(Hh, a_src, a_dst, rowptr, eidx, b2, Ah_g);

    // final FC -> fp32 out
    const dim3 gg3(OUT / 128, Mp / 128);
    mfma_gemm<<<gg3, 256, 0, stream>>>(Ah_g, Wt3, nullptr, out, bfc,
                                       nullptr, nullptr, nullptr, nullptr, Nn, OUT, HC);
}

// Round 5
// 603.021 us; speedup vs baseline: 2.6065x; 1.1754x over previous
//
#include <hip/hip_runtime.h>
#include <cfloat>
#include <cstdint>

#define HEADS 4
#define HIDC 128
#define HC 512
#define NEG 0.2f

typedef _Float16 half8 __attribute__((ext_vector_type(8)));
typedef _Float16 half2v __attribute__((ext_vector_type(2)));
typedef float floatx4 __attribute__((ext_vector_type(4)));

// ---------------- f16 MFMA GEMM ----------------
// C = A[Mp,K] @ Bt[N,K]^T. 128x128 tile, BK=32, 4 waves 2x2, each 64x64 via
// 4x4 mfma_f32_16x16x32_f16. Staging via global_load_lds width=16.
// Outputs: Ch (f16, layers) or Cf (fp32+bias, final FC).
// If atts != null (N==512): fuse a_src/a_dst per-head dot into epilogue
// (blockIdx.x == head since cols-per-block == HIDC == 128).
__global__ __launch_bounds__(256) void mfma_gemm(
    const _Float16* __restrict__ A,   // [Mp][K]
    const _Float16* __restrict__ Bt,  // [N][K]
    _Float16* __restrict__ Ch,        // [Mp][N] f16 out (or null)
    float* __restrict__ Cf,           // [M][N] fp32 out (or null)
    const float* __restrict__ bias,   // [N] (with Cf) or null
    const float* __restrict__ atts,   // [HEADS][128] or null
    const float* __restrict__ attd,
    float* __restrict__ a_src,        // [M][4]
    float* __restrict__ a_dst,
    int M, int N, int K)
{
    __shared__ __align__(16) _Float16 As[128 * 32];
    __shared__ __align__(16) _Float16 Bs[128 * 32];

    const int tid = threadIdx.x;
    const int w = tid >> 6;
    const int lane = tid & 63;
    const int wr = (w >> 1) * 64;
    const int wc = (w & 1) * 64;

    const int rowBase = blockIdx.y * 128;
    const int colBase = blockIdx.x * 128;

    const int sRow0 = (w * 2 + 0) * 16 + (lane >> 2);
    const int sRow1 = (w * 2 + 1) * 16 + (lane >> 2);
    const int sCol = (lane & 3) * 8;

    const _Float16* gA0 = A + (size_t)(rowBase + sRow0) * K + sCol;
    const _Float16* gA1 = A + (size_t)(rowBase + sRow1) * K + sCol;
    const _Float16* gB0 = Bt + (size_t)(colBase + sRow0) * K + sCol;
    const _Float16* gB1 = Bt + (size_t)(colBase + sRow1) * K + sCol;

    _Float16* lA0 = &As[(w * 2 + 0) * 512];
    _Float16* lA1 = &As[(w * 2 + 1) * 512];
    _Float16* lB0 = &Bs[(w * 2 + 0) * 512];
    _Float16* lB1 = &Bs[(w * 2 + 1) * 512];

    floatx4 acc[4][4];
#pragma unroll
    for (int i = 0; i < 4; i++)
#pragma unroll
        for (int j = 0; j < 4; j++) acc[i][j] = {0.f, 0.f, 0.f, 0.f};

    const int q = lane >> 4;
    const int l16 = lane & 15;

    for (int k0 = 0; k0 < K; k0 += 32) {
        __builtin_amdgcn_global_load_lds(
            (const __attribute__((address_space(1))) unsigned int*)(gA0 + k0),
            (__attribute__((address_space(3))) unsigned int*)lA0, 16, 0, 0);
        __builtin_amdgcn_global_load_lds(
            (const __attribute__((address_space(1))) unsigned int*)(gA1 + k0),
            (__attribute__((address_space(3))) unsigned int*)lA1, 16, 0, 0);
        __builtin_amdgcn_global_load_lds(
            (const __attribute__((address_space(1))) unsigned int*)(gB0 + k0),
            (__attribute__((address_space(3))) unsigned int*)lB0, 16, 0, 0);
        __builtin_amdgcn_global_load_lds(
            (const __attribute__((address_space(1))) unsigned int*)(gB1 + k0),
            (__attribute__((address_space(3))) unsigned int*)lB1, 16, 0, 0);
        __syncthreads();

        half8 af[4], bf[4];
#pragma unroll
        for (int i = 0; i < 4; i++)
            af[i] = *(const half8*)&As[(wr + i * 16 + l16) * 32 + q * 8];
#pragma unroll
        for (int j = 0; j < 4; j++)
            bf[j] = *(const half8*)&Bs[(wc + j * 16 + l16) * 32 + q * 8];
#pragma unroll
        for (int i = 0; i < 4; i++)
#pragma unroll
            for (int j = 0; j < 4; j++)
                acc[i][j] = __builtin_amdgcn_mfma_f32_16x16x32_f16(af[i], bf[j], acc[i][j], 0, 0, 0);
        __syncthreads();
    }

    // ---- C stores (C/D layout: col=l16, row=q*4+r) ----
    if (Ch) {
#pragma unroll
        for (int i = 0; i < 4; i++)
#pragma unroll
            for (int j = 0; j < 4; j++) {
                const int col = colBase + wc + j * 16 + l16;
#pragma unroll
                for (int r = 0; r < 4; r++) {
                    const int row = rowBase + wr + i * 16 + q * 4 + r;
                    if (row < M) Ch[(size_t)row * N + col] = (_Float16)acc[i][j][r];
                }
            }
    }
    if (Cf) {
#pragma unroll
        for (int i = 0; i < 4; i++)
#pragma unroll
            for (int j = 0; j < 4; j++) {
                const int col = colBase + wc + j * 16 + l16;
                const float bb = bias ? bias[col] : 0.f;
#pragma unroll
                for (int r = 0; r < 4; r++) {
                    const int row = rowBase + wr + i * 16 + q * 4 + r;
                    if (row < M) Cf[(size_t)row * N + col] = acc[i][j][r] + bb;
                }
            }
    }

    // ---- fused attention coefficients (layers only) ----
    if (atts) {
        float* ps = (float*)As;        // [2][128]
        float* pd = ps + 256;          // [2][128]
        const int head = blockIdx.x;
        float as[4], ad[4];
#pragma unroll
        for (int j = 0; j < 4; j++) {
            const int cl = wc + j * 16 + l16;
            as[j] = atts[head * HIDC + cl];
            ad[j] = attd[head * HIDC + cl];
        }
#pragma unroll
        for (int i = 0; i < 4; i++) {
#pragma unroll
            for (int r = 0; r < 4; r++) {
                float s_ = acc[i][0][r] * as[0] + acc[i][1][r] * as[1]
                         + acc[i][2][r] * as[2] + acc[i][3][r] * as[3];
                float d_ = acc[i][0][r] * ad[0] + acc[i][1][r] * ad[1]
                         + acc[i][2][r] * ad[2] + acc[i][3][r] * ad[3];
#pragma unroll
                for (int mk = 1; mk <= 8; mk <<= 1) {
                    s_ += __shfl_xor(s_, mk);
                    d_ += __shfl_xor(d_, mk);
                }
                if (l16 == 0) {
                    const int rloc = wr + i * 16 + q * 4 + r;
                    ps[(wc >> 6) * 128 + rloc] = s_;
                    pd[(wc >> 6) * 128 + rloc] = d_;
                }
            }
        }
        __syncthreads();
        if (tid < 128) {
            const int row = rowBase + tid;
            if (row < M) {
                a_src[(size_t)row * 4 + head] = ps[tid] + ps[128 + tid];
                a_dst[(size_t)row * 4 + head] = pd[tid] + pd[128 + tid];
            }
        }
    }
}

// ---------------- dtype conversion ----------------
__global__ void convert_x_kernel(const float* __restrict__ x, _Float16* __restrict__ o, size_t nquads)
{
    size_t i = (size_t)blockIdx.x * blockDim.x + threadIdx.x;
    if (i < nquads) {
        float4 v = *(const float4*)(x + i * 4);
        _Float16* p = o + i * 4;
        p[0] = (_Float16)v.x; p[1] = (_Float16)v.y;
        p[2] = (_Float16)v.z; p[3] = (_Float16)v.w;
    }
}

// W[k][n] (fp32) -> Wt[n][k] (f16)
__global__ void convert_wT_kernel(const float* __restrict__ W, _Float16* __restrict__ Wt, int K, int N)
{
    int k = blockIdx.x * 64 + (threadIdx.x & 63);
    int n = blockIdx.y * 4 + (threadIdx.x >> 6);
    if (k < K && n < N) Wt[(size_t)n * K + k] = (_Float16)W[(size_t)k * N + n];
}

// ---------------- CSR build (by dst) ----------------
__global__ void count_kernel(const int* __restrict__ dst, int* __restrict__ deg, int E)
{
    int e = blockIdx.x * blockDim.x + threadIdx.x;
    if (e < E) atomicAdd(&deg[dst[e]], 1);
}

// per-256-chunk degree sums
__global__ __launch_bounds__(256) void block_sum_kernel(
    const int* __restrict__ deg, int* __restrict__ bsum, int Nn)
{
    int gid = blockIdx.x * 256 + threadIdx.x;
    int v = (gid < Nn) ? deg[gid] : 0;
#pragma unroll
    for (int o = 32; o >= 1; o >>= 1) v += __shfl_xor(v, o);
    __shared__ int ws[4];
    if ((threadIdx.x & 63) == 0) ws[threadIdx.x >> 6] = v;
    __syncthreads();
    if (threadIdx.x == 0) bsum[blockIdx.x] = ws[0] + ws[1] + ws[2] + ws[3];
}

// exclusive scan of block sums (nb <= 256), single block
__global__ __launch_bounds__(256) void scan_bsum_kernel(
    const int* __restrict__ bsum, int* __restrict__ bbase, int nb)
{
    __shared__ int s[256];
    const int tid = threadIdx.x;
    int v = (tid < nb) ? bsum[tid] : 0;
    s[tid] = v;
    __syncthreads();
    for (int off = 1; off < 256; off <<= 1) {
        int t = (tid >= off) ? s[tid - off] : 0;
        __syncthreads();
        s[tid] += t;
        __syncthreads();
    }
    if (tid < nb) bbase[tid] = s[tid] - v;
}

// in-block exclusive scan + block base -> rowptr/cursor
__global__ __launch_bounds__(256) void fill_rowptr_kernel(
    const int* __restrict__ deg, const int* __restrict__ bbase,
    int* __restrict__ rowptr, int* __restrict__ cursor, int Nn, int E)
{
    __shared__ int s[256];
    const int tid = threadIdx.x;
    const int gid = blockIdx.x * 256 + tid;
    int v = (gid < Nn) ? deg[gid] : 0;
    s[tid] = v;
    __syncthreads();
    for (int off = 1; off < 256; off <<= 1) {
        int t = (tid >= off) ? s[tid - off] : 0;
        __syncthreads();
        s[tid] += t;
        __syncthreads();
    }
    if (gid < Nn) {
        int r = bbase[blockIdx.x] + s[tid] - v;
        rowptr[gid] = r;
        cursor[gid] = r;
    }
    if (gid == 0) rowptr[Nn] = E;
}

__global__ void fill_kernel(const int* __restrict__ src, const int* __restrict__ dst,
                            int* __restrict__ cursor, int* __restrict__ eidx, int E)
{
    int e = blockIdx.x * blockDim.x + threadIdx.x;
    if (e < E) {
        int d = dst[e];
        int pos = atomicAdd(&cursor[d], 1);
        eidx[pos] = src[e];
    }
}

// ---------------- gather v2: edge-parallel weights + full-row waves ----------------
__global__ __launch_bounds__(256) void gather_kernel(
    const _Float16* __restrict__ h, const float* __restrict__ a_src, const float* __restrict__ a_dst,
    const int* __restrict__ rowptr, const int* __restrict__ eidx,
    const float* __restrict__ bias, _Float16* __restrict__ out)
{
    const int node = blockIdx.x;
    const int tid = threadIdx.x;
    const int wv = tid >> 6;
    const int lane = tid & 63;

    __shared__ __align__(16) float wgt[256][4];
    __shared__ int sidx[256];
    __shared__ float accs[4][HC];
    __shared__ float part[4][4];

    const int beg = rowptr[node];
    const int total = rowptr[node + 1] - beg + 1;   // + virtual self-loop
    const float4 ad4 = *(const float4*)(a_dst + (size_t)node * 4);

    float acc[8];
#pragma unroll
    for (int i = 0; i < 8; i++) acc[i] = 0.f;
    float4 dsum = make_float4(0.f, 0.f, 0.f, 0.f);

    const int hd = lane >> 4;   // head owned by this lane's channels in phase B
    const _Float16* hrow_base = h + (size_t)lane * 8;

    for (int off = 0; off < total; off += 256) {
        const int clen = min(total - off, 256);
        if (tid < clen) {
            const int e = off + tid;
            const int s = (e == total - 1) ? node : eidx[beg + e];
            sidx[tid] = s;
            float4 as4 = *(const float4*)(a_src + (size_t)s * 4);
            float l0 = as4.x + ad4.x; l0 = l0 > 0.f ? l0 : NEG * l0;
            float l1 = as4.y + ad4.y; l1 = l1 > 0.f ? l1 : NEG * l1;
            float l2 = as4.z + ad4.z; l2 = l2 > 0.f ? l2 : NEG * l2;
            float l3 = as4.w + ad4.w; l3 = l3 > 0.f ? l3 : NEG * l3;
            float4 w4 = make_float4(__expf(l0), __expf(l1), __expf(l2), __expf(l3));
            *(float4*)&wgt[tid][0] = w4;
            dsum.x += w4.x; dsum.y += w4.y; dsum.z += w4.z; dsum.w += w4.w;
        }
        __syncthreads();
        for (int e = wv; e < clen; e += 4) {
            const float w = wgt[e][hd];
            const int s = sidx[e];
            half8 hv = *(const half8*)(hrow_base + (size_t)s * HC);
#pragma unroll
            for (int i = 0; i < 8; i++) acc[i] += w * (float)hv[i];
        }
        __syncthreads();
    }

    // block-reduce denominators (per head)
#pragma unroll
    for (int o = 32; o >= 1; o >>= 1) {
        dsum.x += __shfl_xor(dsum.x, o);
        dsum.y += __shfl_xor(dsum.y, o);
        dsum.z += __shfl_xor(dsum.z, o);
        dsum.w += __shfl_xor(dsum.w, o);
    }
    if (lane == 0) {
        part[wv][0] = dsum.x; part[wv][1] = dsum.y;
        part[wv][2] = dsum.z; part[wv][3] = dsum.w;
    }
    // dump per-wave partial accumulators
    float* ap = &accs[wv][lane * 8];
#pragma unroll
    for (int i = 0; i < 8; i++) ap[i] = acc[i];
    __syncthreads();

    // final: thread t owns channels 2t, 2t+1 (same head)
    const int ch = tid * 2;
    const int head = tid >> 6;
    const float is = 1.f / (part[0][head] + part[1][head] + part[2][head] + part[3][head]);
    float t0 = accs[0][ch] + accs[1][ch] + accs[2][ch] + accs[3][ch];
    float t1 = accs[0][ch + 1] + accs[1][ch + 1] + accs[2][ch + 1] + accs[3][ch + 1];
    float2 bv = *(const float2*)(bias + ch);
    float o0 = t0 * is + bv.x; o0 = o0 > 0.f ? o0 : 0.f;
    float o1 = t1 * is + bv.y; o1 = o1 > 0.f ? o1 : 0.f;
    half2v ov; ov.x = (_Float16)o0; ov.y = (_Float16)o1;
    *(half2v*)(out + (size_t)node * HC + ch) = ov;
}

extern "C" void kernel_launch(void* const* d_in, const int* in_sizes, int n_in,
                              void* d_out, int out_size, void* d_ws, size_t ws_size,
                              hipStream_t stream)
{
    const float* x   = (const float*)d_in[0];
    const int*   ei  = (const int*)d_in[1];
    const float* W1  = (const float*)d_in[2];
    const float* a1s = (const float*)d_in[3];
    const float* a1d = (const float*)d_in[4];
    const float* b1  = (const float*)d_in[5];
    const float* W2  = (const float*)d_in[6];
    const float* a2s = (const float*)d_in[7];
    const float* a2d = (const float*)d_in[8];
    const float* b2  = (const float*)d_in[9];
    const float* Wfc = (const float*)d_in[10];
    const float* bfc = (const float*)d_in[11];
    float* out = (float*)d_out;

    const int Nn  = in_sizes[0] / 384;        // 50000
    const int E   = in_sizes[1] / 2;          // 500000
    const int IN  = 384;
    const int OUT = in_sizes[11];             // 384
    const int Mp  = ((Nn + 127) / 128) * 128; // 50048
    const int nb  = (Nn + 255) / 256;         // scan blocks (196)

    uint8_t* p = (uint8_t*)d_ws;
    auto alloc = [&](size_t bytes) {
        uint8_t* r = p;
        p += (bytes + 255) & ~(size_t)255;
        return r;
    };
    _Float16* Ah_x = (_Float16*)alloc((size_t)Mp * IN * 2);   // f16 x
    _Float16* Ah_g = (_Float16*)alloc((size_t)Mp * HC * 2);   // gather outputs (GEMM input)
    _Float16* Hh   = (_Float16*)alloc((size_t)Mp * HC * 2);   // GEMM output h (f16)
    _Float16* Wt1  = (_Float16*)alloc((size_t)HC * IN * 2);
    _Float16* Wt2  = (_Float16*)alloc((size_t)HC * HC * 2);
    _Float16* Wt3  = (_Float16*)alloc((size_t)OUT * HC * 2);
    float* a_src   = (float*)alloc((size_t)Nn * 4 * 4);
    float* a_dst   = (float*)alloc((size_t)Nn * 4 * 4);
    int* deg       = (int*)alloc((size_t)Nn * 4);
    int* rowptr    = (int*)alloc((size_t)(Nn + 1) * 4);
    int* cursor    = (int*)alloc((size_t)Nn * 4);
    int* eidx      = (int*)alloc((size_t)E * 4);
    int* bsum      = (int*)alloc((size_t)nb * 4);
    int* bbase     = (int*)alloc((size_t)nb * 4);

    const int* e_src = ei;
    const int* e_dst = ei + E;

    // conversions
    {
        size_t nq = (size_t)Nn * IN / 4;
        convert_x_kernel<<<(nq + 255) / 256, 256, 0, stream>>>(x, Ah_x, nq);
        dim3 gw1((IN + 63) / 64, HC / 4);
        convert_wT_kernel<<<gw1, 256, 0, stream>>>(W1, Wt1, IN, HC);
        dim3 gw2((HC + 63) / 64, HC / 4);
        convert_wT_kernel<<<gw2, 256, 0, stream>>>(W2, Wt2, HC, HC);
        dim3 gw3((HC + 63) / 64, OUT / 4);
        convert_wT_kernel<<<gw3, 256, 0, stream>>>(Wfc, Wt3, HC, OUT);
    }

    // CSR build (parallel scan)
    hipMemsetAsync(deg, 0, Nn * sizeof(int), stream);
    const int eb = (E + 255) / 256;
    count_kernel<<<eb, 256, 0, stream>>>(e_dst, deg, E);
    block_sum_kernel<<<nb, 256, 0, stream>>>(deg, bsum, Nn);
    scan_bsum_kernel<<<1, 256, 0, stream>>>(bsum, bbase, nb);
    fill_rowptr_kernel<<<nb, 256, 0, stream>>>(deg, bbase, rowptr, cursor, Nn, E);
    fill_kernel<<<eb, 256, 0, stream>>>(e_src, e_dst, cursor, eidx, E);

    const dim3 gg1(HC / 128, Mp / 128);

    // layer 1: GEMM (f16 out) + fused att
    mfma_gemm<<<gg1, 256, 0, stream>>>(Ah_x, Wt1, Hh, nullptr, nullptr,
                                       a1s, a1d, a_src, a_dst, Nn, HC, IN);
    gather_kernel<<<Nn, 256, 0, stream>>>(Hh, a_src, a_dst, rowptr, eidx, b1, Ah_g);

    // layer 2
    mfma_gemm<<<gg1, 256, 0, stream>>>(Ah_g, Wt2, Hh, nullptr, nullptr,
                                       a2s, a2d, a_src, a_dst, Nn, HC, HC);
    gather_kernel<<<Nn, 256, 0, stream>>>(Hh, a_src, a_dst, rowptr, eidx, b2, Ah_g);

    // final FC -> fp32 out
    const dim3 gg3(OUT / 128, Mp / 128);
    mfma_gemm<<<gg3, 256, 0, stream>>>(Ah_g, Wt3, nullptr, out, bfc,
                                       nullptr, nullptr, nullptr, nullptr, Nn, OUT, HC);
}

// Round 6
// 596.328 us; speedup vs baseline: 2.6357x; 1.0112x over previous
//
#include <hip/hip_runtime.h>
#include <cfloat>
#include <cstdint>

#define HEADS 4
#define HIDC 128
#define HC 512
#define NEG 0.2f

typedef _Float16 half8 __attribute__((ext_vector_type(8)));
typedef _Float16 half2v __attribute__((ext_vector_type(2)));
typedef float floatx4 __attribute__((ext_vector_type(4)));

// ---------------- f16 MFMA GEMM ----------------
// C = A[Mp,K] @ Bt[N,K]^T. 128x128 tile, BK=32, 4 waves 2x2, each 64x64 via
// 4x4 mfma_f32_16x16x32_f16. Staging via global_load_lds width=16.
// If atts != null (N==512): fuse a_src/a_dst per-head dot into epilogue.
__global__ __launch_bounds__(256) void mfma_gemm(
    const _Float16* __restrict__ A,   // [Mp][K]
    const _Float16* __restrict__ Bt,  // [N][K]
    _Float16* __restrict__ Ch,        // [Mp][N] f16 out (or null)
    float* __restrict__ Cf,           // [M][N] fp32 out (or null)
    const float* __restrict__ bias,   // [N] (with Cf) or null
    const float* __restrict__ atts,   // [HEADS][128] or null
    const float* __restrict__ attd,
    float* __restrict__ a_src,        // [M][4]
    float* __restrict__ a_dst,
    int M, int N, int K)
{
    __shared__ __align__(16) _Float16 As[128 * 32];
    __shared__ __align__(16) _Float16 Bs[128 * 32];

    const int tid = threadIdx.x;
    const int w = tid >> 6;
    const int lane = tid & 63;
    const int wr = (w >> 1) * 64;
    const int wc = (w & 1) * 64;

    const int rowBase = blockIdx.y * 128;
    const int colBase = blockIdx.x * 128;

    const int sRow0 = (w * 2 + 0) * 16 + (lane >> 2);
    const int sRow1 = (w * 2 + 1) * 16 + (lane >> 2);
    const int sCol = (lane & 3) * 8;

    const _Float16* gA0 = A + (size_t)(rowBase + sRow0) * K + sCol;
    const _Float16* gA1 = A + (size_t)(rowBase + sRow1) * K + sCol;
    const _Float16* gB0 = Bt + (size_t)(colBase + sRow0) * K + sCol;
    const _Float16* gB1 = Bt + (size_t)(colBase + sRow1) * K + sCol;

    _Float16* lA0 = &As[(w * 2 + 0) * 512];
    _Float16* lA1 = &As[(w * 2 + 1) * 512];
    _Float16* lB0 = &Bs[(w * 2 + 0) * 512];
    _Float16* lB1 = &Bs[(w * 2 + 1) * 512];

    floatx4 acc[4][4];
#pragma unroll
    for (int i = 0; i < 4; i++)
#pragma unroll
        for (int j = 0; j < 4; j++) acc[i][j] = {0.f, 0.f, 0.f, 0.f};

    const int q = lane >> 4;
    const int l16 = lane & 15;

    for (int k0 = 0; k0 < K; k0 += 32) {
        __builtin_amdgcn_global_load_lds(
            (const __attribute__((address_space(1))) unsigned int*)(gA0 + k0),
            (__attribute__((address_space(3))) unsigned int*)lA0, 16, 0, 0);
        __builtin_amdgcn_global_load_lds(
            (const __attribute__((address_space(1))) unsigned int*)(gA1 + k0),
            (__attribute__((address_space(3))) unsigned int*)lA1, 16, 0, 0);
        __builtin_amdgcn_global_load_lds(
            (const __attribute__((address_space(1))) unsigned int*)(gB0 + k0),
            (__attribute__((address_space(3))) unsigned int*)lB0, 16, 0, 0);
        __builtin_amdgcn_global_load_lds(
            (const __attribute__((address_space(1))) unsigned int*)(gB1 + k0),
            (__attribute__((address_space(3))) unsigned int*)lB1, 16, 0, 0);
        __syncthreads();

        half8 af[4], bf[4];
#pragma unroll
        for (int i = 0; i < 4; i++)
            af[i] = *(const half8*)&As[(wr + i * 16 + l16) * 32 + q * 8];
#pragma unroll
        for (int j = 0; j < 4; j++)
            bf[j] = *(const half8*)&Bs[(wc + j * 16 + l16) * 32 + q * 8];
#pragma unroll
        for (int i = 0; i < 4; i++)
#pragma unroll
            for (int j = 0; j < 4; j++)
                acc[i][j] = __builtin_amdgcn_mfma_f32_16x16x32_f16(af[i], bf[j], acc[i][j], 0, 0, 0);
        __syncthreads();
    }

    // ---- C stores (C/D layout: col=l16, row=q*4+r) ----
    if (Ch) {
#pragma unroll
        for (int i = 0; i < 4; i++)
#pragma unroll
            for (int j = 0; j < 4; j++) {
                const int col = colBase + wc + j * 16 + l16;
#pragma unroll
                for (int r = 0; r < 4; r++) {
                    const int row = rowBase + wr + i * 16 + q * 4 + r;
                    if (row < M) Ch[(size_t)row * N + col] = (_Float16)acc[i][j][r];
                }
            }
    }
    if (Cf) {
#pragma unroll
        for (int i = 0; i < 4; i++)
#pragma unroll
            for (int j = 0; j < 4; j++) {
                const int col = colBase + wc + j * 16 + l16;
                const float bb = bias ? bias[col] : 0.f;
#pragma unroll
                for (int r = 0; r < 4; r++) {
                    const int row = rowBase + wr + i * 16 + q * 4 + r;
                    if (row < M) Cf[(size_t)row * N + col] = acc[i][j][r] + bb;
                }
            }
    }

    // ---- fused attention coefficients (layers only) ----
    if (atts) {
        float* ps = (float*)As;        // [2][128]
        float* pd = ps + 256;          // [2][128]
        const int head = blockIdx.x;
        float as[4], ad[4];
#pragma unroll
        for (int j = 0; j < 4; j++) {
            const int cl = wc + j * 16 + l16;
            as[j] = atts[head * HIDC + cl];
            ad[j] = attd[head * HIDC + cl];
        }
#pragma unroll
        for (int i = 0; i < 4; i++) {
#pragma unroll
            for (int r = 0; r < 4; r++) {
                float s_ = acc[i][0][r] * as[0] + acc[i][1][r] * as[1]
                         + acc[i][2][r] * as[2] + acc[i][3][r] * as[3];
                float d_ = acc[i][0][r] * ad[0] + acc[i][1][r] * ad[1]
                         + acc[i][2][r] * ad[2] + acc[i][3][r] * ad[3];
#pragma unroll
                for (int mk = 1; mk <= 8; mk <<= 1) {
                    s_ += __shfl_xor(s_, mk);
                    d_ += __shfl_xor(d_, mk);
                }
                if (l16 == 0) {
                    const int rloc = wr + i * 16 + q * 4 + r;
                    ps[(wc >> 6) * 128 + rloc] = s_;
                    pd[(wc >> 6) * 128 + rloc] = d_;
                }
            }
        }
        __syncthreads();
        if (tid < 128) {
            const int row = rowBase + tid;
            if (row < M) {
                a_src[(size_t)row * 4 + head] = ps[tid] + ps[128 + tid];
                a_dst[(size_t)row * 4 + head] = pd[tid] + pd[128 + tid];
            }
        }
    }
}

// ---------------- dtype conversion ----------------
__global__ void convert_x_kernel(const float* __restrict__ x, _Float16* __restrict__ o, size_t nquads)
{
    size_t i = (size_t)blockIdx.x * blockDim.x + threadIdx.x;
    if (i < nquads) {
        float4 v = *(const float4*)(x + i * 4);
        _Float16* p = o + i * 4;
        p[0] = (_Float16)v.x; p[1] = (_Float16)v.y;
        p[2] = (_Float16)v.z; p[3] = (_Float16)v.w;
    }
}

// W[k][n] (fp32) -> Wt[n][k] (f16)
__global__ void convert_wT_kernel(const float* __restrict__ W, _Float16* __restrict__ Wt, int K, int N)
{
    int k = blockIdx.x * 64 + (threadIdx.x & 63);
    int n = blockIdx.y * 4 + (threadIdx.x >> 6);
    if (k < K && n < N) Wt[(size_t)n * K + k] = (_Float16)W[(size_t)k * N + n];
}

// ---------------- CSR build (by dst) ----------------
__global__ void count_kernel(const int* __restrict__ dst, int* __restrict__ deg, int E)
{
    int e = blockIdx.x * blockDim.x + threadIdx.x;
    if (e < E) atomicAdd(&deg[dst[e]], 1);
}

__global__ __launch_bounds__(256) void block_sum_kernel(
    const int* __restrict__ deg, int* __restrict__ bsum, int Nn)
{
    int gid = blockIdx.x * 256 + threadIdx.x;
    int v = (gid < Nn) ? deg[gid] : 0;
#pragma unroll
    for (int o = 32; o >= 1; o >>= 1) v += __shfl_xor(v, o);
    __shared__ int ws[4];
    if ((threadIdx.x & 63) == 0) ws[threadIdx.x >> 6] = v;
    __syncthreads();
    if (threadIdx.x == 0) bsum[blockIdx.x] = ws[0] + ws[1] + ws[2] + ws[3];
}

__global__ __launch_bounds__(256) void scan_bsum_kernel(
    const int* __restrict__ bsum, int* __restrict__ bbase, int nb)
{
    __shared__ int s[256];
    const int tid = threadIdx.x;
    int v = (tid < nb) ? bsum[tid] : 0;
    s[tid] = v;
    __syncthreads();
    for (int off = 1; off < 256; off <<= 1) {
        int t = (tid >= off) ? s[tid - off] : 0;
        __syncthreads();
        s[tid] += t;
        __syncthreads();
    }
    if (tid < nb) bbase[tid] = s[tid] - v;
}

__global__ __launch_bounds__(256) void fill_rowptr_kernel(
    const int* __restrict__ deg, const int* __restrict__ bbase,
    int* __restrict__ rowptr, int* __restrict__ cursor, int Nn, int E)
{
    __shared__ int s[256];
    const int tid = threadIdx.x;
    const int gid = blockIdx.x * 256 + tid;
    int v = (gid < Nn) ? deg[gid] : 0;
    s[tid] = v;
    __syncthreads();
    for (int off = 1; off < 256; off <<= 1) {
        int t = (tid >= off) ? s[tid - off] : 0;
        __syncthreads();
        s[tid] += t;
        __syncthreads();
    }
    if (gid < Nn) {
        int r = bbase[blockIdx.x] + s[tid] - v;
        rowptr[gid] = r;
        cursor[gid] = r;
    }
    if (gid == 0) rowptr[Nn] = E;
}

// fill CSR: src index AND dst per slot (edst needed by edge_weight_kernel)
__global__ void fill_kernel(const int* __restrict__ src, const int* __restrict__ dst,
                            int* __restrict__ cursor, int* __restrict__ eidx,
                            int* __restrict__ edst, int E)
{
    int e = blockIdx.x * blockDim.x + threadIdx.x;
    if (e < E) {
        int d = dst[e];
        int pos = atomicAdd(&cursor[d], 1);
        eidx[pos] = src[e];
        edst[pos] = d;
    }
}

// ---------------- per-edge softmax numerators (CSR order, coalesced out) --------
__global__ __launch_bounds__(256) void edge_weight_kernel(
    const int* __restrict__ eidx, const int* __restrict__ edst,
    const float* __restrict__ a_src, const float* __restrict__ a_dst,
    float4* __restrict__ wedge, int E)
{
    int p = blockIdx.x * 256 + threadIdx.x;
    if (p < E) {
        int s = eidx[p];
        int d = edst[p];
        float4 as4 = *(const float4*)(a_src + (size_t)s * 4);
        float4 ad4 = *(const float4*)(a_dst + (size_t)d * 4);
        float l0 = as4.x + ad4.x; l0 = l0 > 0.f ? l0 : NEG * l0;
        float l1 = as4.y + ad4.y; l1 = l1 > 0.f ? l1 : NEG * l1;
        float l2 = as4.z + ad4.z; l2 = l2 > 0.f ? l2 : NEG * l2;
        float l3 = as4.w + ad4.w; l3 = l3 > 0.f ? l3 : NEG * l3;
        wedge[p] = make_float4(__expf(l0), __expf(l1), __expf(l2), __expf(l3));
    }
}

// ---------------- gather v3: precomputed weights, pipelined row accumulation ------
__global__ __launch_bounds__(256) void gather_kernel(
    const _Float16* __restrict__ h, const float* __restrict__ a_src,
    const float* __restrict__ a_dst,
    const int* __restrict__ rowptr, const int* __restrict__ eidx,
    const float4* __restrict__ wedge,
    const float* __restrict__ bias, _Float16* __restrict__ out)
{
    const int node = blockIdx.x;
    const int tid = threadIdx.x;
    const int wv = tid >> 6;
    const int lane = tid & 63;

    __shared__ __align__(16) float4 wgt[256];
    __shared__ int sidx[256];
    __shared__ float accs[4][HC];
    __shared__ float part[4][4];

    const int beg = rowptr[node];
    const int nE = rowptr[node + 1] - beg;
    const int total = nE + 1;   // + virtual self-loop

    float acc[8];
#pragma unroll
    for (int i = 0; i < 8; i++) acc[i] = 0.f;
    float4 dsum = make_float4(0.f, 0.f, 0.f, 0.f);

    const int hd = lane >> 4;
    const _Float16* hrow_base = h + (size_t)lane * 8;

    for (int off = 0; off < total; off += 256) {
        const int clen = min(total - off, 256);
        if (tid < clen) {
            const int e = off + tid;
            float4 w4;
            int s;
            if (e == nE) {          // virtual self-loop
                s = node;
                float4 as4 = *(const float4*)(a_src + (size_t)node * 4);
                float4 ad4 = *(const float4*)(a_dst + (size_t)node * 4);
                float l0 = as4.x + ad4.x; l0 = l0 > 0.f ? l0 : NEG * l0;
                float l1 = as4.y + ad4.y; l1 = l1 > 0.f ? l1 : NEG * l1;
                float l2 = as4.z + ad4.z; l2 = l2 > 0.f ? l2 : NEG * l2;
                float l3 = as4.w + ad4.w; l3 = l3 > 0.f ? l3 : NEG * l3;
                w4 = make_float4(__expf(l0), __expf(l1), __expf(l2), __expf(l3));
            } else {                // coalesced copies
                s = eidx[beg + e];
                w4 = wedge[beg + e];
            }
            sidx[tid] = s;
            wgt[tid] = w4;
            dsum.x += w4.x; dsum.y += w4.y; dsum.z += w4.z; dsum.w += w4.w;
        }
        __syncthreads();
        // phase B: wave wv takes edges wv, wv+4, ... ; unroll 2 for MLP
        int e = wv;
        for (; e + 4 < clen; e += 8) {
            const int s0 = sidx[e];
            const int s1 = sidx[e + 4];
            const float w0 = ((const float*)&wgt[e])[hd];
            const float w1 = ((const float*)&wgt[e + 4])[hd];
            half8 hv0 = *(const half8*)(hrow_base + (size_t)s0 * HC);
            half8 hv1 = *(const half8*)(hrow_base + (size_t)s1 * HC);
#pragma unroll
            for (int i = 0; i < 8; i++) acc[i] += w0 * (float)hv0[i];
#pragma unroll
            for (int i = 0; i < 8; i++) acc[i] += w1 * (float)hv1[i];
        }
        if (e < clen) {
            const int s0 = sidx[e];
            const float w0 = ((const float*)&wgt[e])[hd];
            half8 hv0 = *(const half8*)(hrow_base + (size_t)s0 * HC);
#pragma unroll
            for (int i = 0; i < 8; i++) acc[i] += w0 * (float)hv0[i];
        }
        __syncthreads();
    }

    // block-reduce denominators (per head)
#pragma unroll
    for (int o = 32; o >= 1; o >>= 1) {
        dsum.x += __shfl_xor(dsum.x, o);
        dsum.y += __shfl_xor(dsum.y, o);
        dsum.z += __shfl_xor(dsum.z, o);
        dsum.w += __shfl_xor(dsum.w, o);
    }
    if (lane == 0) {
        part[wv][0] = dsum.x; part[wv][1] = dsum.y;
        part[wv][2] = dsum.z; part[wv][3] = dsum.w;
    }
    float* ap = &accs[wv][lane * 8];
#pragma unroll
    for (int i = 0; i < 8; i++) ap[i] = acc[i];
    __syncthreads();

    // final: thread t owns channels 2t, 2t+1
    const int ch = tid * 2;
    const int head = tid >> 6;
    const float is = 1.f / (part[0][head] + part[1][head] + part[2][head] + part[3][head]);
    float t0 = accs[0][ch] + accs[1][ch] + accs[2][ch] + accs[3][ch];
    float t1 = accs[0][ch + 1] + accs[1][ch + 1] + accs[2][ch + 1] + accs[3][ch + 1];
    float2 bv = *(const float2*)(bias + ch);
    float o0 = t0 * is + bv.x; o0 = o0 > 0.f ? o0 : 0.f;
    float o1 = t1 * is + bv.y; o1 = o1 > 0.f ? o1 : 0.f;
    half2v ov; ov.x = (_Float16)o0; ov.y = (_Float16)o1;
    *(half2v*)(out + (size_t)node * HC + ch) = ov;
}

extern "C" void kernel_launch(void* const* d_in, const int* in_sizes, int n_in,
                              void* d_out, int out_size, void* d_ws, size_t ws_size,
                              hipStream_t stream)
{
    const float* x   = (const float*)d_in[0];
    const int*   ei  = (const int*)d_in[1];
    const float* W1  = (const float*)d_in[2];
    const float* a1s = (const float*)d_in[3];
    const float* a1d = (const float*)d_in[4];
    const float* b1  = (const float*)d_in[5];
    const float* W2  = (const float*)d_in[6];
    const float* a2s = (const float*)d_in[7];
    const float* a2d = (const float*)d_in[8];
    const float* b2  = (const float*)d_in[9];
    const float* Wfc = (const float*)d_in[10];
    const float* bfc = (const float*)d_in[11];
    float* out = (float*)d_out;

    const int Nn  = in_sizes[0] / 384;        // 50000
    const int E   = in_sizes[1] / 2;          // 500000
    const int IN  = 384;
    const int OUT = in_sizes[11];             // 384
    const int Mp  = ((Nn + 127) / 128) * 128; // 50048
    const int nb  = (Nn + 255) / 256;         // scan blocks (196)

    uint8_t* p = (uint8_t*)d_ws;
    auto alloc = [&](size_t bytes) {
        uint8_t* r = p;
        p += (bytes + 255) & ~(size_t)255;
        return r;
    };
    _Float16* Ah_x = (_Float16*)alloc((size_t)Mp * IN * 2);   // f16 x
    _Float16* Ah_g = (_Float16*)alloc((size_t)Mp * HC * 2);   // gather outputs (GEMM input)
    _Float16* Hh   = (_Float16*)alloc((size_t)Mp * HC * 2);   // GEMM output h (f16)
    _Float16* Wt1  = (_Float16*)alloc((size_t)HC * IN * 2);
    _Float16* Wt2  = (_Float16*)alloc((size_t)HC * HC * 2);
    _Float16* Wt3  = (_Float16*)alloc((size_t)OUT * HC * 2);
    float* a_src   = (float*)alloc((size_t)Nn * 4 * 4);
    float* a_dst   = (float*)alloc((size_t)Nn * 4 * 4);
    int* deg       = (int*)alloc((size_t)Nn * 4);
    int* rowptr    = (int*)alloc((size_t)(Nn + 1) * 4);
    int* cursor    = (int*)alloc((size_t)Nn * 4);
    int* eidx      = (int*)alloc((size_t)E * 4);
    int* edst      = (int*)alloc((size_t)E * 4);
    float4* wedge  = (float4*)alloc((size_t)E * 16);
    int* bsum      = (int*)alloc((size_t)nb * 4);
    int* bbase     = (int*)alloc((size_t)nb * 4);

    const int* e_src = ei;
    const int* e_dst = ei + E;

    // conversions
    {
        size_t nq = (size_t)Nn * IN / 4;
        convert_x_kernel<<<(nq + 255) / 256, 256, 0, stream>>>(x, Ah_x, nq);
        dim3 gw1((IN + 63) / 64, HC / 4);
        convert_wT_kernel<<<gw1, 256, 0, stream>>>(W1, Wt1, IN, HC);
        dim3 gw2((HC + 63) / 64, HC / 4);
        convert_wT_kernel<<<gw2, 256, 0, stream>>>(W2, Wt2, HC, HC);
        dim3 gw3((HC + 63) / 64, OUT / 4);
        convert_wT_kernel<<<gw3, 256, 0, stream>>>(Wfc, Wt3, HC, OUT);
    }

    // CSR build (parallel scan)
    hipMemsetAsync(deg, 0, Nn * sizeof(int), stream);
    const int eb = (E + 255) / 256;
    count_kernel<<<eb, 256, 0, stream>>>(e_dst, deg, E);
    block_sum_kernel<<<nb, 256, 0, stream>>>(deg, bsum, Nn);
    scan_bsum_kernel<<<1, 256, 0, stream>>>(bsum, bbase, nb);
    fill_rowptr_kernel<<<nb, 256, 0, stream>>>(deg, bbase, rowptr, cursor, Nn, E);
    fill_kernel<<<eb, 256, 0, stream>>>(e_src, e_dst, cursor, eidx, edst, E);

    const dim3 gg1(HC / 128, Mp / 128);

    // layer 1
    mfma_gemm<<<gg1, 256, 0, stream>>>(Ah_x, Wt1, Hh, nullptr, nullptr,
                                       a1s, a1d, a_src, a_dst, Nn, HC, IN);
    edge_weight_kernel<<<eb, 256, 0, stream>>>(eidx, edst, a_src, a_dst, wedge, E);
    gather_kernel<<<Nn, 256, 0, stream>>>(Hh, a_src, a_dst, rowptr, eidx, wedge, b1, Ah_g);

    // layer 2
    mfma_gemm<<<gg1, 256, 0, stream>>>(Ah_g, Wt2, Hh, nullptr, nullptr,
                                       a2s, a2d, a_src, a_dst, Nn, HC, HC);
    edge_weight_kernel<<<eb, 256, 0, stream>>>(eidx, edst, a_src, a_dst, wedge, E);
    gather_kernel<<<Nn, 256, 0, stream>>>(Hh, a_src, a_dst, rowptr, eidx, wedge, b2, Ah_g);

    // final FC -> fp32 out
    const dim3 gg3(OUT / 128, Mp / 128);
    mfma_gemm<<<gg3, 256, 0, stream>>>(Ah_g, Wt3, nullptr, out, bfc,
                                       nullptr, nullptr, nullptr, nullptr, Nn, OUT, HC);
}